// Round 9
// baseline (494.788 us; speedup 1.0000x reference)
//
#include <hip/hip_runtime.h>
#include <stdint.h>

#define B_ 2
#define S_ 2048
#define DIM_ 2048
#define H_ 16
#define KVH_ 4
#define HD_ 128

typedef short short8 __attribute__((ext_vector_type(8)));
typedef float f4 __attribute__((ext_vector_type(4)));
typedef float f16v __attribute__((ext_vector_type(16)));
typedef unsigned int uint2v __attribute__((ext_vector_type(2)));
typedef unsigned short u16;

// softmax scale folded into Q at attn load: 1/sqrt(128) * log2(e)
#define KSCALE (0.08838834764831845f * 1.4426950408889634f)

__device__ __forceinline__ float bf2f(u16 u) {
    union { unsigned int i; float f; } c; c.i = ((unsigned int)u) << 16; return c.f;
}
__device__ __forceinline__ u16 f2bf(float f) {
    union { float f; unsigned int i; } c; c.f = f;
    return (u16)((c.i + 0x7fffu + ((c.i >> 16) & 1u)) >> 16);
}
__device__ __forceinline__ unsigned pk_bf16(float lo, float hi) {
    unsigned r;
    asm("v_cvt_pk_bf16_f32 %0, %1, %2" : "=v"(r) : "v"(lo), "v"(hi));
    return r;
}

// async global->LDS, 16B per lane; LDS dest is wave-uniform base + lane*16
#define GLDS16(gp, lp) \
    __builtin_amdgcn_global_load_lds((const __attribute__((address_space(1))) unsigned int*)(gp), \
                                     (__attribute__((address_space(3))) unsigned int*)(lp), 16, 0, 0)

#define BAR()     asm volatile("s_barrier" ::: "memory")
#define WAITLGKM() asm volatile("s_waitcnt lgkmcnt(0)" ::: "memory")
#define SCHEDB()  __builtin_amdgcn_sched_barrier(0)

// ---------------- fused fp32 -> bf16 cast of all 5 tensors ----------------
__global__ void cast_all(const float* __restrict__ x,  const float* __restrict__ wq,
                         const float* __restrict__ wk, const float* __restrict__ wv,
                         const float* __restrict__ wo,
                         u16* __restrict__ xb, u16* __restrict__ wqkvb, u16* __restrict__ wob) {
    int i = blockIdx.x * 256 + threadIdx.x;   // float4 index, total 4718592
    const float4* src; ushort4* dst; int j;
    if (i < 2097152)      { src = (const float4*)x;  dst = (ushort4*)xb;                 j = i; }
    else if (i < 3145728) { src = (const float4*)wq; dst = (ushort4*)wqkvb;              j = i - 2097152; }
    else if (i < 3407872) { src = (const float4*)wk; dst = (ushort4*)wqkvb + 1048576;    j = i - 3145728; }
    else if (i < 3670016) { src = (const float4*)wv; dst = (ushort4*)wqkvb + 1310720;    j = i - 3407872; }
    else                  { src = (const float4*)wo; dst = (ushort4*)wob;                j = i - 3670016; }
    float4 v = src[j];
    ushort4 o;
    o.x = f2bf(v.x); o.y = f2bf(v.y); o.z = f2bf(v.z); o.w = f2bf(v.w);
    dst[j] = o;
}

// ---------------- GEMM: 256x256 tile, 8-wave, 4-phase/K-tile, counted-vmcnt pipeline ----
// (unchanged — passing)
template<bool OUT_BF16, int NBX>
__global__ __launch_bounds__(512, 2) void gemm256(const u16* __restrict__ A,
                                                  const u16* __restrict__ W,
                                                  void* __restrict__ Cout,
                                                  int M, int N, int K) {
    __shared__ u16 As[2][16384];
    __shared__ u16 Bs[2][16384];
    int t = threadIdx.x, lane = t & 63, w = t >> 6;          // 8 waves
    int quad = lane >> 4, l16 = lane & 15, l7 = lane & 7;
    int wm = w >> 2, wn = w & 3;                              // 2M x 4N wave grid
    int bid = blockIdx.x;
    int xcd = bid & 7, grp = bid >> 3;
    int bx = grp % NBX, by = (grp / NBX) * 8 + xcd;
    size_t m0 = (size_t)by * 256, n0 = (size_t)bx * 256;

    // staging lane map: row += lane>>3, 16B unit = (lane&7) ^ (lane>>3)  (XOR swizzle)
    int srow = lane >> 3;
    int sunit = (lane & 7) ^ srow;
    int rR0a = (w >> 2) * 64 + (w & 3) * 8;   // strided-region wave base
    const u16* Ag = A + (m0 + srow) * (size_t)K + sunit * 8;
    const u16* Bg = W + (n0 + srow) * (size_t)K + sunit * 8;

#define STG_A(pl, tk, r0) GLDS16(Ag + ((size_t)((r0) + w * 8)) * K + (tk) * 64, (pl) + ((r0) + w * 8) * 64)
#define STG_B(pl, tk, r0) GLDS16(Bg + ((size_t)((r0) + w * 8)) * K + (tk) * 64, (pl) + ((r0) + w * 8) * 64)
#define STG_BR(pl, tk, bse) GLDS16(Bg + ((size_t)((bse) + rR0a)) * K + (tk) * 64, (pl) + ((bse) + rR0a) * 64)

#define LDA(mh) { \
    _Pragma("unroll") for (int i_ = 0; i_ < 4; i_++) \
    _Pragma("unroll") for (int k_ = 0; k_ < 2; k_++) \
        a[i_][k_] = *(const short8*)&pAc[(wm * 128 + (mh) * 64 + i_ * 16 + l16) * 64 + (((quad + 4 * k_) ^ l7) << 3)]; }
#define LDB(nh) { \
    _Pragma("unroll") for (int j_ = 0; j_ < 2; j_++) \
    _Pragma("unroll") for (int k_ = 0; k_ < 2; k_++) \
        b[j_][k_] = *(const short8*)&pBc[(wn * 64 + (nh) * 32 + j_ * 16 + l16) * 64 + (((quad + 4 * k_) ^ l7) << 3)]; }
#define MFMA_Q(mh, nh) { \
    __builtin_amdgcn_s_setprio(1); \
    _Pragma("unroll") for (int i_ = 0; i_ < 4; i_++) \
    _Pragma("unroll") for (int j_ = 0; j_ < 2; j_++) \
    _Pragma("unroll") for (int k_ = 0; k_ < 2; k_++) \
        acc[(mh) * 4 + i_][(nh) * 2 + j_] = __builtin_amdgcn_mfma_f32_16x16x32_bf16( \
            a[i_][k_], b[j_][k_], acc[(mh) * 4 + i_][(nh) * 2 + j_], 0, 0, 0); \
    __builtin_amdgcn_s_setprio(0); }

    f4 acc[8][4];
    #pragma unroll
    for (int i = 0; i < 8; i++)
        #pragma unroll
        for (int j = 0; j < 4; j++) acc[i][j] = (f4){0.f, 0.f, 0.f, 0.f};

    int NT = K >> 6;

    // prologue: fully stage tiles 0 and 1, drain once
    #pragma unroll
    for (int pt = 0; pt < 2; pt++) {
        u16* pa = &As[pt][0]; u16* pb = &Bs[pt][0];
        #pragma unroll
        for (int r0 = 0; r0 < 256; r0 += 64) { STG_A(pa, pt, r0); STG_B(pb, pt, r0); }
    }
    asm volatile("s_waitcnt vmcnt(0)" ::: "memory");
    BAR();

    short8 a[4][2], b[2][2];
    for (int tt = 0; tt < NT; tt++) {
        int c = tt & 1, nc = c ^ 1;
        u16* pAc = &As[c][0];  u16* pBc = &Bs[c][0];
        u16* pAn = &As[nc][0]; u16* pBn = &Bs[nc][0];
        bool s1 = (tt >= 1) & (tt + 1 < NT);
        bool s2 = (tt + 2 < NT);
        // ---- ph0: quadrant (0,0)
        LDA(0); LDB(0);
        if (s1) { STG_A(pAn, tt + 1, 64); STG_A(pAn, tt + 1, 192); }
        BAR(); WAITLGKM(); MFMA_Q(0, 0); BAR();
        // ---- ph1: quadrant (0,1)
        LDB(1);
        if (s1) { STG_BR(pBn, tt + 1, 32); STG_BR(pBn, tt + 1, 160); }
        BAR(); WAITLGKM(); MFMA_Q(0, 1); BAR();
        // ---- ph2: quadrant (1,0)
        LDA(1); LDB(0);
        if (s2) { STG_A(pAc, tt + 2, 0); STG_A(pAc, tt + 2, 128); }
        BAR(); WAITLGKM(); MFMA_Q(1, 0); BAR();
        // ---- ph3: quadrant (1,1); single counted wait per tile
        if (s2) asm volatile("s_waitcnt vmcnt(2)" ::: "memory");
        else    asm volatile("s_waitcnt vmcnt(0)" ::: "memory");
        LDB(1);
        if (s2) { STG_BR(pBc, tt + 2, 0); STG_BR(pBc, tt + 2, 128); }
        BAR(); WAITLGKM(); MFMA_Q(1, 1); BAR();
    }

    #pragma unroll
    for (int i = 0; i < 8; i++) {
        size_t row = m0 + wm * 128 + i * 16 + quad * 4;
        #pragma unroll
        for (int j = 0; j < 4; j++) {
            size_t col = n0 + wn * 64 + j * 16 + l16;
            #pragma unroll
            for (int r = 0; r < 4; r++) {
                if (OUT_BF16) ((u16*)Cout)[(row + r) * (size_t)N + col] = f2bf(acc[i][j][r]);
                else          ((float*)Cout)[(row + r) * (size_t)N + col] = acc[i][j][r];
            }
        }
    }
#undef STG_A
#undef STG_B
#undef STG_BR
#undef LDA
#undef LDB
#undef MFMA_Q
}

// ---------------- pack K (fused RoPE) into FRAGMENT-CONTIGUOUS order ----------------
__global__ __launch_bounds__(256) void pack_k(const u16* __restrict__ QKV,
                                              const float* __restrict__ freqs,
                                              u16* __restrict__ Kp) {
    int gid = blockIdx.x * 256 + threadIdx.x;   // 262144
    int lane = gid & 63, j = (gid >> 6) & 1, ds = (gid >> 7) & 7;
    int kt = (gid >> 10) & 31, bk = gid >> 15;
    int b = bk >> 2, kvh = bk & 3;
    int l31 = lane & 31, hi = lane >> 5;
    int s = kt * 64 + j * 32 + l31;
    int d0 = ds * 16 + hi * 8;
    const u16* src = QKV + (size_t)(b * S_ + s) * 3072 + 2048 + kvh * HD_ + d0;
    short8 v = *(const short8*)src;
    short8 o;
    #pragma unroll
    for (int jp = 0; jp < 4; jp++) {
        float2 cw = ((const float2*)freqs)[s * 64 + ds * 8 + hi * 4 + jp];
        float x0 = bf2f((u16)v[2 * jp]), x1 = bf2f((u16)v[2 * jp + 1]);
        o[2 * jp]     = (short)f2bf(x0 * cw.x - x1 * cw.y);
        o[2 * jp + 1] = (short)f2bf(x0 * cw.y + x1 * cw.x);
    }
    *(short8*)&Kp[(size_t)gid * 8] = o;
}

// ---------------- pack V^T into FRAGMENT-CONTIGUOUS order ----------------
__global__ __launch_bounds__(256) void pack_v(const u16* __restrict__ QKV, u16* __restrict__ Vp) {
    __shared__ u16 L[64 * 136];
    int bid = blockIdx.x;          // 256 blocks
    int bk = bid & 7, kt = bid >> 3;
    int b = bk >> 2, kvh = bk & 3;
    int t = threadIdx.x;
    const u16* src = QKV + (size_t)(b * S_ + kt * 64) * 3072 + 2560 + kvh * HD_;
    #pragma unroll
    for (int it = 0; it < 4; it++) {
        int idx = t + it * 256;
        int r = idx >> 4, c = idx & 15;
        *(short8*)&L[r * 136 + c * 8] = *(const short8*)(src + (size_t)r * 3072 + c * 8);
    }
    __syncthreads();
    u16* dst = Vp + (size_t)(bk * 32 + kt) * 8192;
    #pragma unroll
    for (int it = 0; it < 4; it++) {
        int idx = t + it * 256;     // 1024 units: frag = idx>>6, lane = idx&63
        int frag = idx >> 6, lane = idx & 63;
        int ks = frag >> 2, ht = frag & 3;
        int hd = ht * 32 + (lane & 31);
        int k0 = ks * 16 + (lane >> 5) * 8;
        short8 v;
        #pragma unroll
        for (int jj = 0; jj < 8; jj++) v[jj] = (short)L[(k0 + jj) * 136 + hd];
        *(short8*)&dst[(size_t)idx * 8] = v;
    }
}

// per-q-tile softmax + P-pack, fully static names (no pointer selection — rule #20)
#define SOFTMAX_PACK(sacc, m_i, ls, o4, pa) { \
    float mx[16]; \
    _Pragma("unroll") for (int r = 0; r < 16; r++) mx[r] = fmaxf(sacc[0][r], sacc[1][r]); \
    _Pragma("unroll") for (int s_ = 8; s_ > 0; s_ >>= 1) \
        _Pragma("unroll") for (int r = 0; r < s_; r++) mx[r] = fmaxf(mx[r], mx[r + s_]); \
    float pm = fmaxf(mx[0], __shfl_xor(mx[0], 32, 64)); \
    if (__any(pm > m_i + 8.0f)) { \
        float mnew = fmaxf(m_i, pm); \
        float al = exp2f(m_i - mnew); \
        ls *= al; \
        _Pragma("unroll") for (int q_ = 0; q_ < 4; q_++) \
            _Pragma("unroll") for (int r = 0; r < 16; r++) o4[q_][r] *= al; \
        m_i = mnew; \
    } \
    _Pragma("unroll") for (int k2 = 0; k2 < 2; k2++) { \
        float p[16]; \
        _Pragma("unroll") for (int r = 0; r < 16; r++) p[r] = exp2f(sacc[k2][r] - m_i); \
        float s0 = (p[0] + p[1]) + (p[2] + p[3]); \
        float s1 = (p[4] + p[5]) + (p[6] + p[7]); \
        float s2 = (p[8] + p[9]) + (p[10] + p[11]); \
        float s3 = (p[12] + p[13]) + (p[14] + p[15]); \
        ls += (s0 + s1) + (s2 + s3); \
        unsigned W0 = pk_bf16(p[0], p[1]),   W1 = pk_bf16(p[2], p[3]); \
        unsigned W2 = pk_bf16(p[4], p[5]),   W3 = pk_bf16(p[6], p[7]); \
        unsigned W4 = pk_bf16(p[8], p[9]),   W5 = pk_bf16(p[10], p[11]); \
        unsigned W6 = pk_bf16(p[12], p[13]), W7 = pk_bf16(p[14], p[15]); \
        uint2v r02 = __builtin_amdgcn_permlane32_swap(W0, W2, false, false); \
        uint2v r13 = __builtin_amdgcn_permlane32_swap(W1, W3, false, false); \
        uint2v r46 = __builtin_amdgcn_permlane32_swap(W4, W6, false, false); \
        uint2v r57 = __builtin_amdgcn_permlane32_swap(W5, W7, false, false); \
        union { unsigned u[4]; short8 s8; } flo, fhi; \
        flo.u[0] = r02[0]; flo.u[1] = r13[0]; flo.u[2] = r02[1]; flo.u[3] = r13[1]; \
        fhi.u[0] = r46[0]; fhi.u[1] = r57[0]; fhi.u[2] = r46[1]; fhi.u[3] = r57[1]; \
        pa[k2 * 2]     = flo.s8; \
        pa[k2 * 2 + 1] = fhi.s8; \
    } }

// ---------------- Flash attention: q-tile-PAIR per wave (fragment reuse), 1 wave/block ----
// R5-R7 post-mortem: attn is bound by per-CU global-load throughput (~20 B/cyc measured:
// R6 4.2MB/CU in 201K cyc; R7's +partial traffic regressed linearly). Fix: each wave owns
// the adjacent q-tile pair (2i, 2i+1) — identical kv-range (nkt=i+1), so each 32KB K+V
// tile read serves 64 MFMA instead of 32 -> per-CU bytes halve (4.2 -> 2.1 MB => ~44us).
// Grid 1024 (4 blocks/CU, VGPR ~380 -> 4 waves/CU resident). Per-CU worklists
// {u+1,16-u,17+u,32-u} sum to 66 pair-tiles; port cap is CU-shared so drain is uniform.
// Masking at last tile: even-qb: k2=0 partial + k2=1 full; odd-qb: k2=1 partial only.
__global__ __launch_bounds__(64, 1)
void attn_kernel(const u16* __restrict__ QKV,
                 const float* __restrict__ freqs,
                 const u16* __restrict__ Kp,
                 const u16* __restrict__ Vp,
                 u16* __restrict__ Ob) {
    int bid = blockIdx.x;          // 1024
    int c = bid & 255, t = bid >> 8;             // t in [0,4)
    int bk = c & 7, h4 = (c >> 3) & 3, u = c >> 5;   // u in [0,8)
    int i = (t == 0) ? (31 - u) : (t == 1) ? (16 + u) : (t == 2) ? (15 - u) : u;
    int qbE = 2 * i;               // even q-tile of the pair; odd = qbE+1
    int nkt = i + 1;
    int b = bk >> 2, kvh = bk & 3;
    int lane = threadIdx.x;
    int l31 = lane & 31, hi = lane >> 5;
    int h = kvh * 4 + h4;

    // ---- Q pair: RoPE + KSCALE in-register, B-fragment layout ----
    short8 qE[8], qO[8];
    {
        int s = qbE * 32 + l31;
        const u16* qp = QKV + ((size_t)(b * S_ + s)) * 3072 + h * HD_ + hi * 8;
        const float2* fr2 = (const float2*)freqs;
        #pragma unroll
        for (int ds = 0; ds < 8; ds++) {
            short8 v0 = *(const short8*)(qp + ds * 16);
            short8 v1 = *(const short8*)(qp + 32 * 3072 + ds * 16);
            short8 oE, oO;
            #pragma unroll
            for (int jp = 0; jp < 4; jp++) {
                float2 csE = fr2[s * 64 + ds * 8 + hi * 4 + jp];
                float2 csO = fr2[(s + 32) * 64 + ds * 8 + hi * 4 + jp];
                float x0 = bf2f((u16)v0[2 * jp]), x1 = bf2f((u16)v0[2 * jp + 1]);
                oE[2 * jp]     = (short)f2bf((x0 * csE.x - x1 * csE.y) * KSCALE);
                oE[2 * jp + 1] = (short)f2bf((x0 * csE.y + x1 * csE.x) * KSCALE);
                float y0 = bf2f((u16)v1[2 * jp]), y1 = bf2f((u16)v1[2 * jp + 1]);
                oO[2 * jp]     = (short)f2bf((y0 * csO.x - y1 * csO.y) * KSCALE);
                oO[2 * jp + 1] = (short)f2bf((y0 * csO.y + y1 * csO.x) * KSCALE);
            }
            qE[ds] = oE; qO[ds] = oO;
        }
    }

    float mE = -3e38f, lsE = 0.f, mO = -3e38f, lsO = 0.f;
    f16v oE4[4], oO4[4];
    #pragma unroll
    for (int q_ = 0; q_ < 4; q_++)
        #pragma unroll
        for (int r = 0; r < 16; r++) { oE4[q_][r] = 0.f; oO4[q_][r] = 0.f; }

    const u16* Kpb = Kp + (size_t)bk * 32 * 8192 + lane * 8;
    const u16* Vpb = Vp + (size_t)bk * 32 * 8192 + lane * 8;

    // prologue: K tile 0 into registers
    short8 kf[16];
    #pragma unroll
    for (int f = 0; f < 16; f++) kf[f] = *(const short8*)(Kpb + f * 512);

    for (int kt = 0; kt < nkt; kt++) {
        // ---- S^T = K . Q^T for BOTH q-tiles on shared kf (the fragment reuse) ----
        f16v sE[2], sO[2];
        #pragma unroll
        for (int k2 = 0; k2 < 2; k2++)
            #pragma unroll
            for (int r = 0; r < 16; r++) { sE[k2][r] = 0.f; sO[k2][r] = 0.f; }
        __builtin_amdgcn_s_setprio(1);
        #pragma unroll
        for (int ds = 0; ds < 8; ds++) {
            sE[0] = __builtin_amdgcn_mfma_f32_32x32x16_bf16(kf[ds * 2],     qE[ds], sE[0], 0, 0, 0);
            sE[1] = __builtin_amdgcn_mfma_f32_32x32x16_bf16(kf[ds * 2 + 1], qE[ds], sE[1], 0, 0, 0);
            sO[0] = __builtin_amdgcn_mfma_f32_32x32x16_bf16(kf[ds * 2],     qO[ds], sO[0], 0, 0, 0);
            sO[1] = __builtin_amdgcn_mfma_f32_32x32x16_bf16(kf[ds * 2 + 1], qO[ds], sO[1], 0, 0, 0);
        }
        __builtin_amdgcn_s_setprio(0);
        SCHEDB();

        // ---- issue all 16 V(t) loads (latency hides under softmax) ----
        short8 vf[16];
        {
            const u16* vb = Vpb + (size_t)kt * 8192;
            #pragma unroll
            for (int f = 0; f < 16; f++) vf[f] = *(const short8*)(vb + f * 512);
        }
        SCHEDB();

        // ---- issue all 16 K(t+1) loads (kf dead after QK) ----
        if (kt + 1 < nkt) {
            const u16* kb = Kpb + (size_t)(kt + 1) * 8192;
            #pragma unroll
            for (int f = 0; f < 16; f++) kf[f] = *(const short8*)(kb + f * 512);
        }
        SCHEDB();

        // ---- causal mask, last tile only ----
        if (kt == nkt - 1) {
            #pragma unroll
            for (int r = 0; r < 16; r++) {
                int colo = (r & 3) + ((r >> 2) << 3) + (hi << 2);
                if (colo > l31) { sE[0][r] = -3e38f; sO[1][r] = -3e38f; }
                sE[1][r] = -3e38f;   // even qb: cols 32..63 all future
            }
        }

        // ---- online softmax + P-pack, q-tile E then O (static names, no ptr select) ----
        short8 paE[4], paO[4];
        SOFTMAX_PACK(sE, mE, lsE, oE4, paE);
        SOFTMAX_PACK(sO, mO, lsO, oO4, paO);
        SCHEDB();

        // ---- O^T += V^T . P^T for BOTH q-tiles on shared vf ----
        __builtin_amdgcn_s_setprio(1);
        #pragma unroll
        for (int ks = 0; ks < 4; ks++) {
            #pragma unroll
            for (int ht = 0; ht < 4; ht++) {
                oE4[ht] = __builtin_amdgcn_mfma_f32_32x32x16_bf16(vf[ks * 4 + ht], paE[ks], oE4[ht], 0, 0, 0);
                oO4[ht] = __builtin_amdgcn_mfma_f32_32x32x16_bf16(vf[ks * 4 + ht], paO[ks], oO4[ht], 0, 0, 0);
            }
        }
        __builtin_amdgcn_s_setprio(0);
    }

    // ---- epilogue, both q-tiles ----
    lsE += __shfl_xor(lsE, 32, 64);
    lsO += __shfl_xor(lsO, 32, 64);
    float rlE = 1.0f / lsE, rlO = 1.0f / lsO;
    size_t row = (size_t)b * S_ + qbE * 32 + l31;
    u16* opE = Ob + row * 2048 + h * HD_;
    u16* opO = opE + (size_t)32 * 2048;
    #pragma unroll
    for (int ht = 0; ht < 4; ht++) {
        #pragma unroll
        for (int g = 0; g < 4; g++) {
            ushort4 stE, stO;
            stE.x = f2bf(oE4[ht][4 * g + 0] * rlE);
            stE.y = f2bf(oE4[ht][4 * g + 1] * rlE);
            stE.z = f2bf(oE4[ht][4 * g + 2] * rlE);
            stE.w = f2bf(oE4[ht][4 * g + 3] * rlE);
            *(ushort4*)&opE[ht * 32 + g * 8 + hi * 4] = stE;
            stO.x = f2bf(oO4[ht][4 * g + 0] * rlO);
            stO.y = f2bf(oO4[ht][4 * g + 1] * rlO);
            stO.z = f2bf(oO4[ht][4 * g + 2] * rlO);
            stO.w = f2bf(oO4[ht][4 * g + 3] * rlO);
            *(ushort4*)&opO[ht * 32 + g * 8 + hi * 4] = stO;
        }
    }
}

extern "C" void kernel_launch(void* const* d_in, const int* in_sizes, int n_in,
                              void* d_out, int out_size, void* d_ws, size_t ws_size,
                              hipStream_t stream) {
    const float* x     = (const float*)d_in[0];
    const float* freqs = (const float*)d_in[1];
    const float* wq    = (const float*)d_in[2];
    const float* wk    = (const float*)d_in[3];
    const float* wv    = (const float*)d_in[4];
    const float* wo    = (const float*)d_in[5];
    float* out = (float*)d_out;

    char* p = (char*)d_ws;
    u16* xb    = (u16*)p; p += (size_t)4096 * 2048 * 2;   // 16MB
    u16* wqkvb = (u16*)p; p += (size_t)3072 * 2048 * 2;   // 12MB
    u16* wob   = (u16*)p; p += (size_t)2048 * 2048 * 2;   // 8MB
    u16* QKVb  = (u16*)p; p += (size_t)4096 * 3072 * 2;   // 24MB
    u16* Kpb   = (u16*)p; p += (size_t)8 * 32 * 8192 * 2; // 4MB
    u16* Vpb   = (u16*)p; p += (size_t)8 * 32 * 8192 * 2; // 4MB
    u16* attnb = xb;  // reuse: x not needed after QKV GEMM

    cast_all<<<18432, 256, 0, stream>>>(x, wq, wk, wv, wo, xb, wqkvb, wob);

    gemm256<true, 12><<<192, 512, 0, stream>>>(xb, wqkvb, QKVb, 4096, 3072, 2048);

    pack_k<<<1024, 256, 0, stream>>>(QKVb, freqs, Kpb);
    pack_v<<<256, 256, 0, stream>>>(QKVb, Vpb);

    attn_kernel<<<1024, 64, 0, stream>>>(QKVb, freqs, Kpb, Vpb, attnb);

    gemm256<false, 8><<<128, 512, 0, stream>>>(attnb, wob, out, 4096, 2048, 2048);
}

// Round 10
// 363.974 us; speedup vs baseline: 1.3594x; 1.3594x over previous
//
#include <hip/hip_runtime.h>
#include <stdint.h>

#define B_ 2
#define S_ 2048
#define DIM_ 2048
#define H_ 16
#define KVH_ 4
#define HD_ 128

typedef short short8 __attribute__((ext_vector_type(8)));
typedef float f4 __attribute__((ext_vector_type(4)));
typedef float f16v __attribute__((ext_vector_type(16)));
typedef unsigned int uint2v __attribute__((ext_vector_type(2)));
typedef unsigned short u16;

// softmax scale folded into Q at attn load: 1/sqrt(128) * log2(e)
#define KSCALE (0.08838834764831845f * 1.4426950408889634f)

__device__ __forceinline__ float bf2f(u16 u) {
    union { unsigned int i; float f; } c; c.i = ((unsigned int)u) << 16; return c.f;
}
__device__ __forceinline__ u16 f2bf(float f) {
    union { float f; unsigned int i; } c; c.f = f;
    return (u16)((c.i + 0x7fffu + ((c.i >> 16) & 1u)) >> 16);
}
__device__ __forceinline__ unsigned pk_bf16(float lo, float hi) {
    unsigned r;
    asm("v_cvt_pk_bf16_f32 %0, %1, %2" : "=v"(r) : "v"(lo), "v"(hi));
    return r;
}

// async global->LDS, 16B per lane; LDS dest is wave-uniform base + lane*16
#define GLDS16(gp, lp) \
    __builtin_amdgcn_global_load_lds((const __attribute__((address_space(1))) unsigned int*)(gp), \
                                     (__attribute__((address_space(3))) unsigned int*)(lp), 16, 0, 0)

#define BAR()     asm volatile("s_barrier" ::: "memory")
#define WAITLGKM() asm volatile("s_waitcnt lgkmcnt(0)" ::: "memory")

// ---------------- fused fp32 -> bf16 cast of all 5 tensors ----------------
__global__ void cast_all(const float* __restrict__ x,  const float* __restrict__ wq,
                         const float* __restrict__ wk, const float* __restrict__ wv,
                         const float* __restrict__ wo,
                         u16* __restrict__ xb, u16* __restrict__ wqkvb, u16* __restrict__ wob) {
    int i = blockIdx.x * 256 + threadIdx.x;   // float4 index, total 4718592
    const float4* src; ushort4* dst; int j;
    if (i < 2097152)      { src = (const float4*)x;  dst = (ushort4*)xb;                 j = i; }
    else if (i < 3145728) { src = (const float4*)wq; dst = (ushort4*)wqkvb;              j = i - 2097152; }
    else if (i < 3407872) { src = (const float4*)wk; dst = (ushort4*)wqkvb + 1048576;    j = i - 3145728; }
    else if (i < 3670016) { src = (const float4*)wv; dst = (ushort4*)wqkvb + 1310720;    j = i - 3407872; }
    else                  { src = (const float4*)wo; dst = (ushort4*)wob;                j = i - 3670016; }
    float4 v = src[j];
    ushort4 o;
    o.x = f2bf(v.x); o.y = f2bf(v.y); o.z = f2bf(v.z); o.w = f2bf(v.w);
    dst[j] = o;
}

// ---------------- GEMM: 256x256 tile, 8-wave, 4-phase/K-tile, counted-vmcnt pipeline ----
// (unchanged — passing)
template<bool OUT_BF16, int NBX>
__global__ __launch_bounds__(512, 2) void gemm256(const u16* __restrict__ A,
                                                  const u16* __restrict__ W,
                                                  void* __restrict__ Cout,
                                                  int M, int N, int K) {
    __shared__ u16 As[2][16384];
    __shared__ u16 Bs[2][16384];
    int t = threadIdx.x, lane = t & 63, w = t >> 6;          // 8 waves
    int quad = lane >> 4, l16 = lane & 15, l7 = lane & 7;
    int wm = w >> 2, wn = w & 3;                              // 2M x 4N wave grid
    int bid = blockIdx.x;
    int xcd = bid & 7, grp = bid >> 3;
    int bx = grp % NBX, by = (grp / NBX) * 8 + xcd;
    size_t m0 = (size_t)by * 256, n0 = (size_t)bx * 256;

    // staging lane map: row += lane>>3, 16B unit = (lane&7) ^ (lane>>3)  (XOR swizzle)
    int srow = lane >> 3;
    int sunit = (lane & 7) ^ srow;
    int rR0a = (w >> 2) * 64 + (w & 3) * 8;   // strided-region wave base
    const u16* Ag = A + (m0 + srow) * (size_t)K + sunit * 8;
    const u16* Bg = W + (n0 + srow) * (size_t)K + sunit * 8;

#define STG_A(pl, tk, r0) GLDS16(Ag + ((size_t)((r0) + w * 8)) * K + (tk) * 64, (pl) + ((r0) + w * 8) * 64)
#define STG_B(pl, tk, r0) GLDS16(Bg + ((size_t)((r0) + w * 8)) * K + (tk) * 64, (pl) + ((r0) + w * 8) * 64)
#define STG_BR(pl, tk, bse) GLDS16(Bg + ((size_t)((bse) + rR0a)) * K + (tk) * 64, (pl) + ((bse) + rR0a) * 64)

#define LDA(mh) { \
    _Pragma("unroll") for (int i_ = 0; i_ < 4; i_++) \
    _Pragma("unroll") for (int k_ = 0; k_ < 2; k_++) \
        a[i_][k_] = *(const short8*)&pAc[(wm * 128 + (mh) * 64 + i_ * 16 + l16) * 64 + (((quad + 4 * k_) ^ l7) << 3)]; }
#define LDB(nh) { \
    _Pragma("unroll") for (int j_ = 0; j_ < 2; j_++) \
    _Pragma("unroll") for (int k_ = 0; k_ < 2; k_++) \
        b[j_][k_] = *(const short8*)&pBc[(wn * 64 + (nh) * 32 + j_ * 16 + l16) * 64 + (((quad + 4 * k_) ^ l7) << 3)]; }
#define MFMA_Q(mh, nh) { \
    __builtin_amdgcn_s_setprio(1); \
    _Pragma("unroll") for (int i_ = 0; i_ < 4; i_++) \
    _Pragma("unroll") for (int j_ = 0; j_ < 2; j_++) \
    _Pragma("unroll") for (int k_ = 0; k_ < 2; k_++) \
        acc[(mh) * 4 + i_][(nh) * 2 + j_] = __builtin_amdgcn_mfma_f32_16x16x32_bf16( \
            a[i_][k_], b[j_][k_], acc[(mh) * 4 + i_][(nh) * 2 + j_], 0, 0, 0); \
    __builtin_amdgcn_s_setprio(0); }

    f4 acc[8][4];
    #pragma unroll
    for (int i = 0; i < 8; i++)
        #pragma unroll
        for (int j = 0; j < 4; j++) acc[i][j] = (f4){0.f, 0.f, 0.f, 0.f};

    int NT = K >> 6;

    // prologue: fully stage tiles 0 and 1, drain once
    #pragma unroll
    for (int pt = 0; pt < 2; pt++) {
        u16* pa = &As[pt][0]; u16* pb = &Bs[pt][0];
        #pragma unroll
        for (int r0 = 0; r0 < 256; r0 += 64) { STG_A(pa, pt, r0); STG_B(pb, pt, r0); }
    }
    asm volatile("s_waitcnt vmcnt(0)" ::: "memory");
    BAR();

    short8 a[4][2], b[2][2];
    for (int tt = 0; tt < NT; tt++) {
        int c = tt & 1, nc = c ^ 1;
        u16* pAc = &As[c][0];  u16* pBc = &Bs[c][0];
        u16* pAn = &As[nc][0]; u16* pBn = &Bs[nc][0];
        bool s1 = (tt >= 1) & (tt + 1 < NT);
        bool s2 = (tt + 2 < NT);
        // ---- ph0: quadrant (0,0)
        LDA(0); LDB(0);
        if (s1) { STG_A(pAn, tt + 1, 64); STG_A(pAn, tt + 1, 192); }
        BAR(); WAITLGKM(); MFMA_Q(0, 0); BAR();
        // ---- ph1: quadrant (0,1)
        LDB(1);
        if (s1) { STG_BR(pBn, tt + 1, 32); STG_BR(pBn, tt + 1, 160); }
        BAR(); WAITLGKM(); MFMA_Q(0, 1); BAR();
        // ---- ph2: quadrant (1,0)
        LDA(1); LDB(0);
        if (s2) { STG_A(pAc, tt + 2, 0); STG_A(pAc, tt + 2, 128); }
        BAR(); WAITLGKM(); MFMA_Q(1, 0); BAR();
        // ---- ph3: quadrant (1,1); single counted wait per tile
        if (s2) asm volatile("s_waitcnt vmcnt(2)" ::: "memory");
        else    asm volatile("s_waitcnt vmcnt(0)" ::: "memory");
        LDB(1);
        if (s2) { STG_BR(pBc, tt + 2, 0); STG_BR(pBc, tt + 2, 128); }
        BAR(); WAITLGKM(); MFMA_Q(1, 1); BAR();
    }

    #pragma unroll
    for (int i = 0; i < 8; i++) {
        size_t row = m0 + wm * 128 + i * 16 + quad * 4;
        #pragma unroll
        for (int j = 0; j < 4; j++) {
            size_t col = n0 + wn * 64 + j * 16 + l16;
            #pragma unroll
            for (int r = 0; r < 4; r++) {
                if (OUT_BF16) ((u16*)Cout)[(row + r) * (size_t)N + col] = f2bf(acc[i][j][r]);
                else          ((float*)Cout)[(row + r) * (size_t)N + col] = acc[i][j][r];
            }
        }
    }
#undef STG_A
#undef STG_B
#undef STG_BR
#undef LDA
#undef LDB
#undef MFMA_Q
}

// ---------------- pack K (fused RoPE) into FRAGMENT-CONTIGUOUS order ----------------
__global__ __launch_bounds__(256) void pack_k(const u16* __restrict__ QKV,
                                              const float* __restrict__ freqs,
                                              u16* __restrict__ Kp) {
    int gid = blockIdx.x * 256 + threadIdx.x;   // 262144
    int lane = gid & 63, j = (gid >> 6) & 1, ds = (gid >> 7) & 7;
    int kt = (gid >> 10) & 31, bk = gid >> 15;
    int b = bk >> 2, kvh = bk & 3;
    int l31 = lane & 31, hi = lane >> 5;
    int s = kt * 64 + j * 32 + l31;
    int d0 = ds * 16 + hi * 8;
    const u16* src = QKV + (size_t)(b * S_ + s) * 3072 + 2048 + kvh * HD_ + d0;
    short8 v = *(const short8*)src;
    short8 o;
    #pragma unroll
    for (int jp = 0; jp < 4; jp++) {
        float2 cw = ((const float2*)freqs)[s * 64 + ds * 8 + hi * 4 + jp];
        float x0 = bf2f((u16)v[2 * jp]), x1 = bf2f((u16)v[2 * jp + 1]);
        o[2 * jp]     = (short)f2bf(x0 * cw.x - x1 * cw.y);
        o[2 * jp + 1] = (short)f2bf(x0 * cw.y + x1 * cw.x);
    }
    *(short8*)&Kp[(size_t)gid * 8] = o;
}

// ---------------- pack V^T into FRAGMENT-CONTIGUOUS order ----------------
__global__ __launch_bounds__(256) void pack_v(const u16* __restrict__ QKV, u16* __restrict__ Vp) {
    __shared__ u16 L[64 * 136];
    int bid = blockIdx.x;          // 256 blocks
    int bk = bid & 7, kt = bid >> 3;
    int b = bk >> 2, kvh = bk & 3;
    int t = threadIdx.x;
    const u16* src = QKV + (size_t)(b * S_ + kt * 64) * 3072 + 2560 + kvh * HD_;
    #pragma unroll
    for (int it = 0; it < 4; it++) {
        int idx = t + it * 256;
        int r = idx >> 4, c = idx & 15;
        *(short8*)&L[r * 136 + c * 8] = *(const short8*)(src + (size_t)r * 3072 + c * 8);
    }
    __syncthreads();
    u16* dst = Vp + (size_t)(bk * 32 + kt) * 8192;
    #pragma unroll
    for (int it = 0; it < 4; it++) {
        int idx = t + it * 256;     // 1024 units: frag = idx>>6, lane = idx&63
        int frag = idx >> 6, lane = idx & 63;
        int ks = frag >> 2, ht = frag & 3;
        int hd = ht * 32 + (lane & 31);
        int k0 = ks * 16 + (lane >> 5) * 8;
        short8 v;
        #pragma unroll
        for (int jj = 0; jj < 8; jj++) v[jj] = (short)L[(k0 + jj) * 136 + hd];
        *(short8*)&dst[(size_t)idx * 8] = v;
    }
}

// ---------------- Flash attention: kv-split for 3 waves/SIMD concurrency ----------------
// R5-R9 post-mortem: ALL whole-task variants sit at ~84us with ~2 waves/SIMD resident —
// traffic varied 4x (R1 vs R6) with no effect, so latency-bound at fixed concurrency=2.
// 2048 wave-tasks / 256 CU = 8 waves/CU = 2/SIMD regardless of blocking. Fix: (a) split
// qb>=32 tasks into 2 kv-chunks -> more, shorter tasks (grid 4096, qb<32 chunk1 exits);
// (b) VGPR <= 170 via JIT fragment loads (no 16-reg batches — R5==R6 proved batching
// neutral) + __launch_bounds__(64,3) -> 3 waves/SIMD resident, 12-16 blocks/CU queued
// (dynamic dispatch self-balances; heavy qb dispatched first). Partials+combine from R7
// (verified passing). WATCH: WRITE_SIZE ~48MB expected; >>that means spill (R9 lesson).
__global__ __launch_bounds__(64, 3)
void attn_kernel(const u16* __restrict__ QKV,
                 const float* __restrict__ freqs,
                 const u16* __restrict__ Kp,
                 const u16* __restrict__ Vp,
                 u16* __restrict__ Ob,
                 float* __restrict__ Po,
                 float* __restrict__ Pm,
                 int split_ok) {
    int bid = blockIdx.x;            // 4096
    int qb = 63 - (bid >> 6);
    int c2 = bid & 63;
    int bk = c2 & 7, h4 = (c2 >> 3) & 3, chunk = (c2 >> 5) & 1;
    int nkt = (qb >> 1) + 1;
    int split = split_ok && (qb >= 32);
    if (!split && chunk) return;     // wave-uniform early exit
    int nh = (nkt + 1) >> 1;
    int kt0 = (split && chunk) ? nh : 0;
    int kt1 = split ? (chunk ? nkt : nh) : nkt;

    int b = bk >> 2, kvh = bk & 3;
    int lane = threadIdx.x;
    int l31 = lane & 31, hi = lane >> 5;
    int h = kvh * 4 + h4;

    // ---- Q: 32 rows (row = l31), RoPE + KSCALE in-register, B-fragment layout ----
    short8 qf[8];
    {
        int s = qb * 32 + l31;
        const u16* qp = QKV + ((size_t)(b * S_ + s)) * 3072 + h * HD_ + hi * 8;
        const float2* fr2 = (const float2*)freqs;
        #pragma unroll
        for (int ds = 0; ds < 8; ds++) {
            short8 v = *(const short8*)(qp + ds * 16);
            short8 o;
            #pragma unroll
            for (int jp = 0; jp < 4; jp++) {
                float2 cs = fr2[s * 64 + ds * 8 + hi * 4 + jp];
                float x0 = bf2f((u16)v[2 * jp]), x1 = bf2f((u16)v[2 * jp + 1]);
                o[2 * jp]     = (short)f2bf((x0 * cs.x - x1 * cs.y) * KSCALE);
                o[2 * jp + 1] = (short)f2bf((x0 * cs.y + x1 * cs.x) * KSCALE);
            }
            qf[ds] = o;
        }
    }

    float m_i = -3e38f, ls = 0.f;
    f16v o4[4];
    #pragma unroll
    for (int i = 0; i < 4; i++)
        #pragma unroll
        for (int r = 0; r < 16; r++) o4[i][r] = 0.f;

    const u16* Kpb = Kp + (size_t)bk * 32 * 8192 + lane * 8;
    const u16* Vpb = Vp + (size_t)bk * 32 * 8192 + lane * 8;

    for (int kt = kt0; kt < kt1; kt++) {
        const u16* kb = Kpb + (size_t)kt * 8192;
        const u16* vb = Vpb + (size_t)kt * 8192;

        // ---- S^T = K . Q^T : JIT fragment loads (TLP at 3/SIMD hides latency) ----
        f16v sacc[2];
        #pragma unroll
        for (int k2 = 0; k2 < 2; k2++)
            #pragma unroll
            for (int r = 0; r < 16; r++) sacc[k2][r] = 0.f;
        __builtin_amdgcn_s_setprio(1);
        #pragma unroll
        for (int ds = 0; ds < 8; ds++) {
            short8 kf0 = *(const short8*)(kb + ds * 1024);
            short8 kf1 = *(const short8*)(kb + ds * 1024 + 512);
            sacc[0] = __builtin_amdgcn_mfma_f32_32x32x16_bf16(kf0, qf[ds], sacc[0], 0, 0, 0);
            sacc[1] = __builtin_amdgcn_mfma_f32_32x32x16_bf16(kf1, qf[ds], sacc[1], 0, 0, 0);
        }
        __builtin_amdgcn_s_setprio(0);

        // ---- causal mask, global diagonal tile only (lives in the last chunk) ----
        if (kt == nkt - 1) {
            int off0 = kt * 64 - qb * 32;
            #pragma unroll
            for (int k2 = 0; k2 < 2; k2++) {
                #pragma unroll
                for (int r = 0; r < 16; r++) {
                    int colo = off0 + k2 * 32 + (r & 3) + ((r >> 2) << 3) + (hi << 2);
                    if (colo > l31) sacc[k2][r] = -3e38f;
                }
            }
        }

        // ---- online softmax; tree max; defer-max THR=8 (T13) ----
        float mx[16];
        #pragma unroll
        for (int r = 0; r < 16; r++) mx[r] = fmaxf(sacc[0][r], sacc[1][r]);
        #pragma unroll
        for (int s_ = 8; s_ > 0; s_ >>= 1)
            #pragma unroll
            for (int r = 0; r < s_; r++) mx[r] = fmaxf(mx[r], mx[r + s_]);
        float pm = fmaxf(mx[0], __shfl_xor(mx[0], 32, 64));
        if (__any(pm > m_i + 8.0f)) {
            float mnew = fmaxf(m_i, pm);
            float al = exp2f(m_i - mnew);
            ls *= al;
            #pragma unroll
            for (int i = 0; i < 4; i++)
                #pragma unroll
                for (int r = 0; r < 16; r++) o4[i][r] *= al;
            m_i = mnew;
        }

        // ---- P = exp2(S - m); tree ls; in-register PV B-fragments (T12) ----
        short8 pa[4];
        #pragma unroll
        for (int k2 = 0; k2 < 2; k2++) {
            float p[16];
            #pragma unroll
            for (int r = 0; r < 16; r++) p[r] = exp2f(sacc[k2][r] - m_i);
            float s0 = (p[0] + p[1]) + (p[2] + p[3]);
            float s1 = (p[4] + p[5]) + (p[6] + p[7]);
            float s2 = (p[8] + p[9]) + (p[10] + p[11]);
            float s3 = (p[12] + p[13]) + (p[14] + p[15]);
            ls += (s0 + s1) + (s2 + s3);
            unsigned W0 = pk_bf16(p[0], p[1]),   W1 = pk_bf16(p[2], p[3]);
            unsigned W2 = pk_bf16(p[4], p[5]),   W3 = pk_bf16(p[6], p[7]);
            unsigned W4 = pk_bf16(p[8], p[9]),   W5 = pk_bf16(p[10], p[11]);
            unsigned W6 = pk_bf16(p[12], p[13]), W7 = pk_bf16(p[14], p[15]);
            uint2v r02 = __builtin_amdgcn_permlane32_swap(W0, W2, false, false);
            uint2v r13 = __builtin_amdgcn_permlane32_swap(W1, W3, false, false);
            uint2v r46 = __builtin_amdgcn_permlane32_swap(W4, W6, false, false);
            uint2v r57 = __builtin_amdgcn_permlane32_swap(W5, W7, false, false);
            union { unsigned u[4]; short8 s8; } flo, fhi;
            flo.u[0] = r02[0]; flo.u[1] = r13[0]; flo.u[2] = r02[1]; flo.u[3] = r13[1];
            fhi.u[0] = r46[0]; fhi.u[1] = r57[0]; fhi.u[2] = r46[1]; fhi.u[3] = r57[1];
            pa[k2 * 2]     = flo.s8;
            pa[k2 * 2 + 1] = fhi.s8;
        }

        // ---- O^T += V^T . P^T : JIT V-fragment loads ----
        __builtin_amdgcn_s_setprio(1);
        #pragma unroll
        for (int ks = 0; ks < 4; ks++) {
            #pragma unroll
            for (int ht = 0; ht < 4; ht++) {
                short8 vf = *(const short8*)(vb + (ks * 4 + ht) * 512);
                o4[ht] = __builtin_amdgcn_mfma_f32_32x32x16_bf16(vf, pa[ks], o4[ht], 0, 0, 0);
            }
        }
        __builtin_amdgcn_s_setprio(0);
    }

    ls += __shfl_xor(ls, 32, 64);   // pair halves hold same q-row, disjoint k
    if (split) {
        // ---- partial epilogue: unnormalized O + (m, ls) ----
        int slot = ((bk * 4 + h4) * 32 + (qb - 32)) * 2 + chunk;
        float* po = Po + (size_t)slot * 4096 + lane * 64;
        #pragma unroll
        for (int ht = 0; ht < 4; ht++)
            #pragma unroll
            for (int r = 0; r < 16; r++) po[ht * 16 + r] = o4[ht][r];
        Pm[(size_t)slot * 128 + lane * 2]     = m_i;
        Pm[(size_t)slot * 128 + lane * 2 + 1] = ls;
    } else {
        // ---- direct epilogue ----
        float rl = 1.0f / ls;
        size_t row = (size_t)b * S_ + qb * 32 + l31;
        u16* op = Ob + row * 2048 + h * HD_;
        #pragma unroll
        for (int ht = 0; ht < 4; ht++) {
            #pragma unroll
            for (int g = 0; g < 4; g++) {
                ushort4 st;
                st.x = f2bf(o4[ht][4 * g + 0] * rl);
                st.y = f2bf(o4[ht][4 * g + 1] * rl);
                st.z = f2bf(o4[ht][4 * g + 2] * rl);
                st.w = f2bf(o4[ht][4 * g + 3] * rl);
                *(ushort4*)&op[ht * 32 + g * 8 + hi * 4] = st;
            }
        }
    }
}

// ---------------- combine the 2 kv-chunks of each qb>=32 task (R7, verified) ----------------
__global__ __launch_bounds__(64) void attn_combine(const float* __restrict__ Po,
                                                   const float* __restrict__ Pm,
                                                   u16* __restrict__ Ob) {
    int cid = blockIdx.x;            // 1024 = 8bk x 4h4 x 32qq
    int bk = cid & 7, h4 = (cid >> 3) & 3, qq = cid >> 5;
    int qb = 32 + qq;
    int b = bk >> 2, kvh = bk & 3;
    int h = kvh * 4 + h4;
    int lane = threadIdx.x;
    int l31 = lane & 31, hi = lane >> 5;
    int s0 = ((bk * 4 + h4) * 32 + qq) * 2;
    float m0 = Pm[(size_t)s0 * 128 + lane * 2],       l0 = Pm[(size_t)s0 * 128 + lane * 2 + 1];
    float m1 = Pm[(size_t)(s0 + 1) * 128 + lane * 2], l1 = Pm[(size_t)(s0 + 1) * 128 + lane * 2 + 1];
    float M  = fmaxf(m0, m1);
    float a0 = exp2f(m0 - M), a1 = exp2f(m1 - M);
    float rl = 1.0f / (l0 * a0 + l1 * a1);
    const float4* q0 = (const float4*)(Po + (size_t)s0 * 4096 + lane * 64);
    const float4* q1 = (const float4*)(Po + (size_t)(s0 + 1) * 4096 + lane * 64);
    size_t row = (size_t)b * S_ + qb * 32 + l31;
    u16* op = Ob + row * 2048 + h * HD_;
    #pragma unroll
    for (int ht = 0; ht < 4; ht++) {
        #pragma unroll
        for (int g = 0; g < 4; g++) {
            float4 v0 = q0[ht * 4 + g], v1 = q1[ht * 4 + g];
            ushort4 st;
            st.x = f2bf((v0.x * a0 + v1.x * a1) * rl);
            st.y = f2bf((v0.y * a0 + v1.y * a1) * rl);
            st.z = f2bf((v0.z * a0 + v1.z * a1) * rl);
            st.w = f2bf((v0.w * a0 + v1.w * a1) * rl);
            *(ushort4*)&op[ht * 32 + g * 8 + hi * 4] = st;
        }
    }
}

extern "C" void kernel_launch(void* const* d_in, const int* in_sizes, int n_in,
                              void* d_out, int out_size, void* d_ws, size_t ws_size,
                              hipStream_t stream) {
    const float* x     = (const float*)d_in[0];
    const float* freqs = (const float*)d_in[1];
    const float* wq    = (const float*)d_in[2];
    const float* wk    = (const float*)d_in[3];
    const float* wv    = (const float*)d_in[4];
    const float* wo    = (const float*)d_in[5];
    float* out = (float*)d_out;

    char* p = (char*)d_ws;
    u16* xb    = (u16*)p; p += (size_t)4096 * 2048 * 2;   // 16MB
    u16* wqkvb = (u16*)p; p += (size_t)3072 * 2048 * 2;   // 12MB
    u16* wob   = (u16*)p; p += (size_t)2048 * 2048 * 2;   // 8MB
    u16* QKVb  = (u16*)p; p += (size_t)4096 * 3072 * 2;   // 24MB
    u16* Kpb   = (u16*)p; p += (size_t)8 * 32 * 8192 * 2; // 4MB
    u16* Vpb   = (u16*)p; p += (size_t)8 * 32 * 8192 * 2; // 4MB
    float* Po  = (float*)p; p += (size_t)2048 * 4096 * 4; // 32MB (kv-split partials O)
    float* Pm  = (float*)p; p += (size_t)2048 * 128 * 4;  // 1MB  (kv-split partials m/ls)
    u16* attnb = xb;  // reuse: x not needed after QKV GEMM

    size_t need = (size_t)(p - (char*)d_ws);
    int split_ok = (ws_size >= need) ? 1 : 0;

    cast_all<<<18432, 256, 0, stream>>>(x, wq, wk, wv, wo, xb, wqkvb, wob);

    gemm256<true, 12><<<192, 512, 0, stream>>>(xb, wqkvb, QKVb, 4096, 3072, 2048);

    pack_k<<<1024, 256, 0, stream>>>(QKVb, freqs, Kpb);
    pack_v<<<256, 256, 0, stream>>>(QKVb, Vpb);

    attn_kernel<<<4096, 64, 0, stream>>>(QKVb, freqs, Kpb, Vpb, attnb, Po, Pm, split_ok);
    if (split_ok) attn_combine<<<1024, 64, 0, stream>>>(Po, Pm, attnb);

    gemm256<false, 8><<<128, 512, 0, stream>>>(attnb, wob, out, 4096, 2048, 2048);
}

// Round 11
// 316.324 us; speedup vs baseline: 1.5642x; 1.1506x over previous
//
#include <hip/hip_runtime.h>
#include <stdint.h>

#define B_ 2
#define S_ 2048
#define DIM_ 2048
#define H_ 16
#define KVH_ 4
#define HD_ 128

typedef short short8 __attribute__((ext_vector_type(8)));
typedef float f4 __attribute__((ext_vector_type(4)));
typedef float f16v __attribute__((ext_vector_type(16)));
typedef unsigned int uint2v __attribute__((ext_vector_type(2)));
typedef unsigned short u16;

// softmax scale folded into Q at attn load: 1/sqrt(128) * log2(e)
#define KSCALE (0.08838834764831845f * 1.4426950408889634f)

__device__ __forceinline__ float bf2f(u16 u) {
    union { unsigned int i; float f; } c; c.i = ((unsigned int)u) << 16; return c.f;
}
__device__ __forceinline__ u16 f2bf(float f) {
    union { float f; unsigned int i; } c; c.f = f;
    return (u16)((c.i + 0x7fffu + ((c.i >> 16) & 1u)) >> 16);
}
__device__ __forceinline__ unsigned pk_bf16(float lo, float hi) {
    unsigned r;
    asm("v_cvt_pk_bf16_f32 %0, %1, %2" : "=v"(r) : "v"(lo), "v"(hi));
    return r;
}

// async global->LDS, 16B per lane; LDS dest is wave-uniform base + lane*16
#define GLDS16(gp, lp) \
    __builtin_amdgcn_global_load_lds((const __attribute__((address_space(1))) unsigned int*)(gp), \
                                     (__attribute__((address_space(3))) unsigned int*)(lp), 16, 0, 0)

#define BAR()     asm volatile("s_barrier" ::: "memory")
#define LGKM0()   asm volatile("s_waitcnt lgkmcnt(0)" ::: "memory")
#define VMCNT0()  asm volatile("s_waitcnt vmcnt(0)" ::: "memory")
#define VMCNT2()  asm volatile("s_waitcnt vmcnt(2)" ::: "memory")

// ---------------- fused fp32 -> bf16 cast of all 5 tensors ----------------
__global__ void cast_all(const float* __restrict__ x,  const float* __restrict__ wq,
                         const float* __restrict__ wk, const float* __restrict__ wv,
                         const float* __restrict__ wo,
                         u16* __restrict__ xb, u16* __restrict__ wqkvb, u16* __restrict__ wob) {
    int i = blockIdx.x * 256 + threadIdx.x;   // float4 index, total 4718592
    const float4* src; ushort4* dst; int j;
    if (i < 2097152)      { src = (const float4*)x;  dst = (ushort4*)xb;                 j = i; }
    else if (i < 3145728) { src = (const float4*)wq; dst = (ushort4*)wqkvb;              j = i - 2097152; }
    else if (i < 3407872) { src = (const float4*)wk; dst = (ushort4*)wqkvb + 1048576;    j = i - 3145728; }
    else if (i < 3670016) { src = (const float4*)wv; dst = (ushort4*)wqkvb + 1310720;    j = i - 3407872; }
    else                  { src = (const float4*)wo; dst = (ushort4*)wob;                j = i - 3670016; }
    float4 v = src[j];
    ushort4 o;
    o.x = f2bf(v.x); o.y = f2bf(v.y); o.z = f2bf(v.z); o.w = f2bf(v.w);
    dst[j] = o;
}

// ---------------- GEMM: faithful 8-phase m201 port (256x256, BK=64, 8 waves) ----------------
// C[M,N] = A[M,K] @ W[N,K]^T.
// Structure per ITERATION (2 K-tiles: t0=2i -> buf0, t1=2i+1 -> buf1; no runtime buffer
// index). Per K-tile, 4 quadrant phases (0,0)(0,1)(1,0)(1,1); B held in b[4][2] so phases
// 3/7 issue ZERO ds_reads. One half-tile staged per phase (8/iter), rotation:
//   ph0: A-h1(t1)   ph1: B-h0(t1)   ph2: B-h1(t1)   ph3: A-h0(t2)
//   ph4: A-h1(t2)   ph5: B-h0(t2)   ph6: B-h1(t2)   ph7: A-h0(t3)
// Each stage targets a region whose last ds_reads drained >=1 barrier earlier (phase's
// lgkmcnt(0) + trailing barrier). Counted vmcnt(2) ONLY at ph3/ph7 end, placed BEFORE the
// barrier so every wave's own loads retire and the barrier publishes; accounting: at ph3,
// outstanding <=10 loads, vmcnt(2) drains everything t1 needs, leaves ph3's own stage.
// vmcnt(0) only in the last iteration's ph3. 8-slot XOR swizzle via pre-swizzled global
// source + XOR'd ds_read (rule #21; field-proven in R2/R3). setprio(1) around MFMA (T5).
template<bool OUT_BF16, int NBX>
__global__ __launch_bounds__(512, 2) void gemm256(const u16* __restrict__ A,
                                                  const u16* __restrict__ W,
                                                  void* __restrict__ Cout,
                                                  int M, int N, int K) {
    __shared__ u16 As[2][16384];
    __shared__ u16 Bs[2][16384];
    int t = threadIdx.x, lane = t & 63, w = t >> 6;          // 8 waves
    int quad = lane >> 4, l16 = lane & 15, l7 = lane & 7;
    int wm = w >> 2, wn = w & 3;                              // 2M x 4N wave grid
    int bid = blockIdx.x;
    int xcd = bid & 7, grp = bid >> 3;
    int bx = grp % NBX, by = (grp / NBX) * 8 + xcd;
    size_t m0 = (size_t)by * 256, n0 = (size_t)bx * 256;

    // staging lane map: row += lane>>3, 16B unit = (lane&7) ^ (lane>>3)  (XOR swizzle)
    int srow = lane >> 3;
    int sunit = (lane & 7) ^ srow;
    const u16* Ag = A + (m0 + srow) * (size_t)K + sunit * 8;
    const u16* Bg = W + (n0 + srow) * (size_t)K + sunit * 8;

#define STG_A(pl, tk, r0) GLDS16(Ag + ((size_t)((r0) + w * 8)) * K + (size_t)(tk) * 64, (pl) + ((r0) + w * 8) * 64)
#define STG_B(pl, tk, r0) GLDS16(Bg + ((size_t)((r0) + w * 8)) * K + (size_t)(tk) * 64, (pl) + ((r0) + w * 8) * 64)

#define LDA(pl, mh) { \
    _Pragma("unroll") for (int i_ = 0; i_ < 4; i_++) \
    _Pragma("unroll") for (int k_ = 0; k_ < 2; k_++) \
        a[i_][k_] = *(const short8*)&(pl)[(wm * 128 + (mh) * 64 + i_ * 16 + l16) * 64 + (((quad + 4 * k_) ^ l7) << 3)]; }
#define LDB(pl, nh) { \
    _Pragma("unroll") for (int j_ = 0; j_ < 2; j_++) \
    _Pragma("unroll") for (int k_ = 0; k_ < 2; k_++) \
        b[(nh) * 2 + j_][k_] = *(const short8*)&(pl)[(wn * 64 + (nh) * 32 + j_ * 16 + l16) * 64 + (((quad + 4 * k_) ^ l7) << 3)]; }
#define MFMA_Q(mh, nh) { \
    __builtin_amdgcn_s_setprio(1); \
    _Pragma("unroll") for (int i_ = 0; i_ < 4; i_++) \
    _Pragma("unroll") for (int j_ = 0; j_ < 2; j_++) \
    _Pragma("unroll") for (int k_ = 0; k_ < 2; k_++) \
        acc[(mh) * 4 + i_][(nh) * 2 + j_] = __builtin_amdgcn_mfma_f32_16x16x32_bf16( \
            a[i_][k_], b[(nh) * 2 + j_][k_], acc[(mh) * 4 + i_][(nh) * 2 + j_], 0, 0, 0); \
    __builtin_amdgcn_s_setprio(0); }

    f4 acc[8][4];
    #pragma unroll
    for (int i = 0; i < 8; i++)
        #pragma unroll
        for (int j = 0; j < 4; j++) acc[i][j] = (f4){0.f, 0.f, 0.f, 0.f};

    int NT = K >> 6;      // 32 K-tiles of BK=64
    int NI = NT >> 1;     // 16 iterations (2 K-tiles each)

    u16* A0p = &As[0][0]; u16* A1p = &As[1][0];
    u16* B0p = &Bs[0][0]; u16* B1p = &Bs[1][0];

    // prologue: fully stage tile 0 -> buf0 and tile 1 -> buf1, drain once
    #pragma unroll
    for (int r0 = 0; r0 < 256; r0 += 64) {
        STG_A(A0p, 0, r0); STG_B(B0p, 0, r0);
        STG_A(A1p, 1, r0); STG_B(B1p, 1, r0);
    }
    VMCNT0();
    BAR();

    short8 a[4][2], b[4][2];
    for (int it = 0; it < NI; it++) {
        int t1 = 2 * it + 1, t2 = 2 * it + 2, t3 = 2 * it + 3;
        bool s1 = (it > 0);          // t1 re-stage (iter 0: prologue covered tile 1)
        bool s2 = (t2 < NT);
        bool s3 = (t3 < NT);
        bool last = (it == NI - 1);

        // ---- ph0: t0 quad(0,0)
        LDA(A0p, 0); LDB(B0p, 0);
        if (s1) { STG_A(A1p, t1, 128); STG_A(A1p, t1, 192); }   // A-h1(t1)
        BAR(); LGKM0(); MFMA_Q(0, 0); BAR();
        // ---- ph1: t0 quad(0,1)
        LDB(B0p, 1);
        if (s1) { STG_B(B1p, t1, 0); STG_B(B1p, t1, 64); }      // B-h0(t1)
        BAR(); LGKM0(); MFMA_Q(0, 1); BAR();
        // ---- ph2: t0 quad(1,0)
        LDA(A0p, 1);
        if (s1) { STG_B(B1p, t1, 128); STG_B(B1p, t1, 192); }   // B-h1(t1)
        BAR(); LGKM0(); MFMA_Q(1, 0); BAR();
        // ---- ph3: t0 quad(1,1); counted wait publishes everything t1 needs
        if (s2) { STG_A(A0p, t2, 0); STG_A(A0p, t2, 64); }      // A-h0(t2)
        if (last) { VMCNT0(); } else { VMCNT2(); }
        BAR(); MFMA_Q(1, 1); BAR();
        // ---- ph4: t1 quad(0,0)
        LDA(A1p, 0); LDB(B1p, 0);
        if (s2) { STG_A(A0p, t2, 128); STG_A(A0p, t2, 192); }   // A-h1(t2)
        BAR(); LGKM0(); MFMA_Q(0, 0); BAR();
        // ---- ph5: t1 quad(0,1)
        LDB(B1p, 1);
        if (s2) { STG_B(B0p, t2, 0); STG_B(B0p, t2, 64); }      // B-h0(t2)
        BAR(); LGKM0(); MFMA_Q(0, 1); BAR();
        // ---- ph6: t1 quad(1,0)
        LDA(A1p, 1);
        if (s2) { STG_B(B0p, t2, 128); STG_B(B0p, t2, 192); }   // B-h1(t2)
        BAR(); LGKM0(); MFMA_Q(1, 0); BAR();
        // ---- ph7: t1 quad(1,1); counted wait publishes everything t2 needs
        if (s3) { STG_A(A1p, t3, 0); STG_A(A1p, t3, 64); }      // A-h0(t3)
        VMCNT2();
        BAR(); MFMA_Q(1, 1); BAR();
    }

    #pragma unroll
    for (int i = 0; i < 8; i++) {
        size_t row = m0 + wm * 128 + i * 16 + quad * 4;
        #pragma unroll
        for (int j = 0; j < 4; j++) {
            size_t col = n0 + wn * 64 + j * 16 + l16;
            #pragma unroll
            for (int r = 0; r < 4; r++) {
                if (OUT_BF16) ((u16*)Cout)[(row + r) * (size_t)N + col] = f2bf(acc[i][j][r]);
                else          ((float*)Cout)[(row + r) * (size_t)N + col] = acc[i][j][r];
            }
        }
    }
#undef STG_A
#undef STG_B
#undef LDA
#undef LDB
#undef MFMA_Q
}

// ---------------- pack K (with fused RoPE) into swizzled row-major tiles (R3) ----------------
__global__ __launch_bounds__(256) void pack_k(const u16* __restrict__ QKV,
                                              const float* __restrict__ freqs,
                                              u16* __restrict__ Kp) {
    int gid = blockIdx.x * 256 + threadIdx.x;   // 262144
    int u = gid & 15, row = (gid >> 4) & 63, kt = (gid >> 10) & 31, bk = gid >> 15;
    int b = bk >> 2, kvh = bk & 3;
    int s = kt * 64 + row;
    int d8 = u ^ (row & 7);
    const u16* src = QKV + (size_t)(b * S_ + s) * 3072 + 2048 + kvh * HD_ + d8 * 8;
    short8 v = *(const short8*)src;
    short8 o;
    #pragma unroll
    for (int jp = 0; jp < 4; jp++) {
        float2 cw = ((const float2*)freqs)[s * 64 + d8 * 4 + jp];
        float x0 = bf2f((u16)v[2 * jp]), x1 = bf2f((u16)v[2 * jp + 1]);
        o[2 * jp]     = (short)f2bf(x0 * cw.x - x1 * cw.y);
        o[2 * jp + 1] = (short)f2bf(x0 * cw.y + x1 * cw.x);
    }
    *(short8*)&Kp[(size_t)gid * 8] = o;
}

// ---------------- pack V transposed (Vt[hd][k]) with same XOR swizzle (R3) ----------------
__global__ __launch_bounds__(256) void pack_v(const u16* __restrict__ QKV, u16* __restrict__ Vp) {
    __shared__ u16 L[64 * 136];
    int bid = blockIdx.x;          // 256 blocks
    int bk = bid & 7, kt = bid >> 3;
    int b = bk >> 2, kvh = bk & 3;
    int t = threadIdx.x;
    const u16* src = QKV + (size_t)(b * S_ + kt * 64) * 3072 + 2560 + kvh * HD_;
    #pragma unroll
    for (int it = 0; it < 4; it++) {
        int idx = t + it * 256;
        int r = idx >> 4, c = idx & 15;
        *(short8*)&L[r * 136 + c * 8] = *(const short8*)(src + (size_t)r * 3072 + c * 8);
    }
    __syncthreads();
    u16* dst = Vp + (size_t)(bk * 32 + kt) * 8192;
    #pragma unroll
    for (int it = 0; it < 4; it++) {
        int idx = t + it * 256;     // 1024 units: hd = idx>>3, u = idx&7
        int hd = idx >> 3, u = idx & 7;
        int k0 = (u ^ (hd & 7)) * 8;
        short8 v;
        #pragma unroll
        for (int jj = 0; jj < 8; jj++) v[jj] = (short)L[(k0 + jj) * 136 + hd];
        *(short8*)&dst[(size_t)idx * 8] = v;
    }
}

// ---------------- Flash attention: R3 version verbatim (best measured: 79.1-79.3 us) ----
// R4-R10 established ~79us as this decomposition's structural floor: invariant under
// inner-loop structure, traffic level (4x range), and concurrency (0.75-1.7 waves/SIMD).
__global__ __launch_bounds__(256) __attribute__((amdgpu_waves_per_eu(2, 2)))
void attn_kernel(const u16* __restrict__ QKV,
                 const float* __restrict__ freqs,
                 const u16* __restrict__ Kp,
                 const u16* __restrict__ Vp,
                 u16* __restrict__ Ob) {
    __shared__ u16 Ks[2][8192];    // 2 x 16KB K tile [64 rows][128 d], XOR-swizzled
    __shared__ u16 Vs[2][8192];    // 2 x 16KB V^T tile [128 hd][64 k], XOR-swizzled
    int bid = blockIdx.x;          // 512
    int jj_ = bid & 255, half = bid >> 8;
    int bk = jj_ & 7, qpr = jj_ >> 3;        // qpr in [0,32)
    int qb = half ? qpr : 63 - qpr;          // long tiles dispatched first
    int b = bk >> 2, kvh = bk & 3;
    int t = threadIdx.x, lane = t & 63, w = t >> 6;
    int l31 = lane & 31, hi = lane >> 5, l7 = lane & 7;
    int h = kvh * 4 + w;
    int nkt = (qb >> 1) + 1;

    // ---- Q: 32 rows (row = l31), RoPE + KSCALE in-register, B-fragment layout ----
    short8 qf[8];
    {
        int s = qb * 32 + l31;
        const u16* qp = QKV + ((size_t)(b * S_ + s)) * 3072 + h * HD_ + hi * 8;
        const float2* fr2 = (const float2*)freqs;
        #pragma unroll
        for (int ds = 0; ds < 8; ds++) {
            short8 v = *(const short8*)(qp + ds * 16);
            short8 o;
            #pragma unroll
            for (int jp = 0; jp < 4; jp++) {
                float2 cs = fr2[s * 64 + ds * 8 + hi * 4 + jp];
                float x0 = bf2f((u16)v[2 * jp]), x1 = bf2f((u16)v[2 * jp + 1]);
                o[2 * jp]     = (short)f2bf((x0 * cs.x - x1 * cs.y) * KSCALE);
                o[2 * jp + 1] = (short)f2bf((x0 * cs.y + x1 * cs.x) * KSCALE);
            }
            qf[ds] = o;
        }
    }

    float m_i = -3e38f, ls = 0.f;
    f16v o4[4];
    #pragma unroll
    for (int i = 0; i < 4; i++)
        #pragma unroll
        for (int r = 0; r < 16; r++) o4[i][r] = 0.f;

    const u16* Kpb = Kp + (size_t)bk * 32 * 8192;
    const u16* Vpb = Vp + (size_t)bk * 32 * 8192;
    int so = w * 2048 + lane * 8;   // this lane's staging slot (u16 units)

    // initial stage of tile 0 into buffer 0 (wave w stages its 4KB quarter of K and V)
    {
        const u16* ks = Kpb + so;
        const u16* vs = Vpb + so;
        #pragma unroll
        for (int i = 0; i < 4; i++) {
            GLDS16(ks + i * 512, &Ks[0][w * 2048 + i * 512]);
            GLDS16(vs + i * 512, &Vs[0][w * 2048 + i * 512]);
        }
    }

    for (int kt = 0; kt < nkt; kt++) {
        int buf = kt & 1;
        __syncthreads();   // drains the stage of tile kt (issued one iteration ago)
        if (kt + 1 < nkt) {
            int nb = buf ^ 1;
            const u16* ks = Kpb + (size_t)(kt + 1) * 8192 + so;
            const u16* vs = Vpb + (size_t)(kt + 1) * 8192 + so;
            #pragma unroll
            for (int i = 0; i < 4; i++) {
                GLDS16(ks + i * 512, &Ks[nb][w * 2048 + i * 512]);
                GLDS16(vs + i * 512, &Vs[nb][w * 2048 + i * 512]);
            }
        }

        // ---- S^T = K . Q^T : D rows = k-pos (crow layout), cols = q (lane&31) ----
        f16v sacc[2];
        #pragma unroll
        for (int k2 = 0; k2 < 2; k2++)
            #pragma unroll
            for (int r = 0; r < 16; r++) sacc[k2][r] = 0.f;
        #pragma unroll
        for (int ds = 0; ds < 8; ds++) {
            int uK = ((ds * 2 + hi) ^ l7) * 8;
            short8 kf0 = *(const short8*)&Ks[buf][l31 * 128 + uK];
            short8 kf1 = *(const short8*)&Ks[buf][(32 + l31) * 128 + uK];
            sacc[0] = __builtin_amdgcn_mfma_f32_32x32x16_bf16(kf0, qf[ds], sacc[0], 0, 0, 0);
            sacc[1] = __builtin_amdgcn_mfma_f32_32x32x16_bf16(kf1, qf[ds], sacc[1], 0, 0, 0);
        }

        // ---- causal mask, diagonal tile only ----
        if (kt == nkt - 1) {
            int off0 = kt * 64 - qb * 32;
            #pragma unroll
            for (int k2 = 0; k2 < 2; k2++) {
                #pragma unroll
                for (int r = 0; r < 16; r++) {
                    int colo = off0 + k2 * 32 + (r & 3) + ((r >> 2) << 3) + (hi << 2);
                    if (colo > l31) sacc[k2][r] = -3e38f;
                }
            }
        }

        // ---- online softmax, per-lane scalars; defer-max THR=8 (T13) ----
        float pm = sacc[0][0];
        #pragma unroll
        for (int r = 1; r < 16; r++) pm = fmaxf(pm, sacc[0][r]);
        #pragma unroll
        for (int r = 0; r < 16; r++) pm = fmaxf(pm, sacc[1][r]);
        pm = fmaxf(pm, __shfl_xor(pm, 32, 64));
        if (__any(pm > m_i + 8.0f)) {
            float mnew = fmaxf(m_i, pm);
            float al = exp2f(m_i - mnew);
            ls *= al;
            #pragma unroll
            for (int i = 0; i < 4; i++)
                #pragma unroll
                for (int r = 0; r < 16; r++) o4[i][r] *= al;
            m_i = mnew;
        }

        // ---- P = exp2(S - m); assemble PV B-fragments in-register (T12) ----
        short8 pa[4];
        #pragma unroll
        for (int k2 = 0; k2 < 2; k2++) {
            float p[16];
            #pragma unroll
            for (int r = 0; r < 16; r++) {
                p[r] = exp2f(sacc[k2][r] - m_i);
                ls += p[r];
            }
            unsigned W0 = pk_bf16(p[0], p[1]),   W1 = pk_bf16(p[2], p[3]);
            unsigned W2 = pk_bf16(p[4], p[5]),   W3 = pk_bf16(p[6], p[7]);
            unsigned W4 = pk_bf16(p[8], p[9]),   W5 = pk_bf16(p[10], p[11]);
            unsigned W6 = pk_bf16(p[12], p[13]), W7 = pk_bf16(p[14], p[15]);
            uint2v r02 = __builtin_amdgcn_permlane32_swap(W0, W2, false, false);
            uint2v r13 = __builtin_amdgcn_permlane32_swap(W1, W3, false, false);
            uint2v r46 = __builtin_amdgcn_permlane32_swap(W4, W6, false, false);
            uint2v r57 = __builtin_amdgcn_permlane32_swap(W5, W7, false, false);
            union { unsigned u[4]; short8 s8; } flo, fhi;
            flo.u[0] = r02[0]; flo.u[1] = r13[0]; flo.u[2] = r02[1]; flo.u[3] = r13[1];
            fhi.u[0] = r46[0]; fhi.u[1] = r57[0]; fhi.u[2] = r46[1]; fhi.u[3] = r57[1];
            pa[k2 * 2]     = flo.s8;
            pa[k2 * 2 + 1] = fhi.s8;
        }

        // ---- O^T += V^T . P^T ----
        #pragma unroll
        for (int ks = 0; ks < 4; ks++) {
            int uV = ((ks * 2 + hi) ^ l7) * 8;
            #pragma unroll
            for (int ht = 0; ht < 4; ht++) {
                short8 vf = *(const short8*)&Vs[buf][(ht * 32 + l31) * 64 + uV];
                o4[ht] = __builtin_amdgcn_mfma_f32_32x32x16_bf16(vf, pa[ks], o4[ht], 0, 0, 0);
            }
        }
    }

    // ---- epilogue ----
    ls += __shfl_xor(ls, 32, 64);
    float rl = 1.0f / ls;
    size_t row = (size_t)b * S_ + qb * 32 + l31;
    u16* op = Ob + row * 2048 + h * HD_;
    #pragma unroll
    for (int ht = 0; ht < 4; ht++) {
        #pragma unroll
        for (int g = 0; g < 4; g++) {
            ushort4 st;
            st.x = f2bf(o4[ht][4 * g + 0] * rl);
            st.y = f2bf(o4[ht][4 * g + 1] * rl);
            st.z = f2bf(o4[ht][4 * g + 2] * rl);
            st.w = f2bf(o4[ht][4 * g + 3] * rl);
            *(ushort4*)&op[ht * 32 + g * 8 + hi * 4] = st;
        }
    }
}

extern "C" void kernel_launch(void* const* d_in, const int* in_sizes, int n_in,
                              void* d_out, int out_size, void* d_ws, size_t ws_size,
                              hipStream_t stream) {
    const float* x     = (const float*)d_in[0];
    const float* freqs = (const float*)d_in[1];
    const float* wq    = (const float*)d_in[2];
    const float* wk    = (const float*)d_in[3];
    const float* wv    = (const float*)d_in[4];
    const float* wo    = (const float*)d_in[5];
    float* out = (float*)d_out;

    char* p = (char*)d_ws;
    u16* xb    = (u16*)p; p += (size_t)4096 * 2048 * 2;   // 16MB
    u16* wqkvb = (u16*)p; p += (size_t)3072 * 2048 * 2;   // 12MB
    u16* wob   = (u16*)p; p += (size_t)2048 * 2048 * 2;   // 8MB
    u16* QKVb  = (u16*)p; p += (size_t)4096 * 3072 * 2;   // 24MB
    u16* Kpb   = (u16*)p; p += (size_t)8 * 32 * 8192 * 2; // 4MB
    u16* Vpb   = (u16*)p; p += (size_t)8 * 32 * 8192 * 2; // 4MB
    u16* attnb = xb;  // reuse: x not needed after QKV GEMM

    cast_all<<<18432, 256, 0, stream>>>(x, wq, wk, wv, wo, xb, wqkvb, wob);

    gemm256<true, 12><<<192, 512, 0, stream>>>(xb, wqkvb, QKVb, 4096, 3072, 2048);

    pack_k<<<1024, 256, 0, stream>>>(QKVb, freqs, Kpb);
    pack_v<<<256, 256, 0, stream>>>(QKVb, Vpb);

    attn_kernel<<<512, 256, 0, stream>>>(QKVb, freqs, Kpb, Vpb, attnb);

    gemm256<false, 8><<<128, 512, 0, stream>>>(attnb, wob, out, 4096, 2048, 2048);
}

// Round 12
// 314.224 us; speedup vs baseline: 1.5746x; 1.0067x over previous
//
#include <hip/hip_runtime.h>
#include <stdint.h>

#define B_ 2
#define S_ 2048
#define DIM_ 2048
#define H_ 16
#define KVH_ 4
#define HD_ 128

typedef short short8 __attribute__((ext_vector_type(8)));
typedef float f4 __attribute__((ext_vector_type(4)));
typedef float f16v __attribute__((ext_vector_type(16)));
typedef unsigned int uint2v __attribute__((ext_vector_type(2)));
typedef unsigned short u16;

// softmax scale folded into Q at attn load: 1/sqrt(128) * log2(e)
#define KSCALE (0.08838834764831845f * 1.4426950408889634f)

__device__ __forceinline__ float bf2f(u16 u) {
    union { unsigned int i; float f; } c; c.i = ((unsigned int)u) << 16; return c.f;
}
__device__ __forceinline__ u16 f2bf(float f) {
    union { float f; unsigned int i; } c; c.f = f;
    return (u16)((c.i + 0x7fffu + ((c.i >> 16) & 1u)) >> 16);
}
__device__ __forceinline__ unsigned pk_bf16(float lo, float hi) {
    unsigned r;
    asm("v_cvt_pk_bf16_f32 %0, %1, %2" : "=v"(r) : "v"(lo), "v"(hi));
    return r;
}

// async global->LDS, 16B per lane; LDS dest is wave-uniform base + lane*16
#define GLDS16(gp, lp) \
    __builtin_amdgcn_global_load_lds((const __attribute__((address_space(1))) unsigned int*)(gp), \
                                     (__attribute__((address_space(3))) unsigned int*)(lp), 16, 0, 0)

#define BAR()     asm volatile("s_barrier" ::: "memory")
#define LGKM0()   asm volatile("s_waitcnt lgkmcnt(0)" ::: "memory")
#define VMCNT0()  asm volatile("s_waitcnt vmcnt(0)" ::: "memory")
#define VMCNT4()  asm volatile("s_waitcnt vmcnt(4)" ::: "memory")

// ---------------- fused fp32 -> bf16 cast of all 5 tensors ----------------
__global__ void cast_all(const float* __restrict__ x,  const float* __restrict__ wq,
                         const float* __restrict__ wk, const float* __restrict__ wv,
                         const float* __restrict__ wo,
                         u16* __restrict__ xb, u16* __restrict__ wqkvb, u16* __restrict__ wob) {
    int i = blockIdx.x * 256 + threadIdx.x;   // float4 index, total 4718592
    const float4* src; ushort4* dst; int j;
    if (i < 2097152)      { src = (const float4*)x;  dst = (ushort4*)xb;                 j = i; }
    else if (i < 3145728) { src = (const float4*)wq; dst = (ushort4*)wqkvb;              j = i - 2097152; }
    else if (i < 3407872) { src = (const float4*)wk; dst = (ushort4*)wqkvb + 1048576;    j = i - 3145728; }
    else if (i < 3670016) { src = (const float4*)wv; dst = (ushort4*)wqkvb + 1310720;    j = i - 3407872; }
    else                  { src = (const float4*)wo; dst = (ushort4*)wob;                j = i - 3670016; }
    float4 v = src[j];
    ushort4 o;
    o.x = f2bf(v.x); o.y = f2bf(v.y); o.z = f2bf(v.z); o.w = f2bf(v.w);
    dst[j] = o;
}

// ---------------- GEMM: 256x256, 8-wave, 4-phase/K-tile, DEEP counted-vmcnt pipeline ----
// C[M,N] = A[M,K] @ W[N,K]^T.
// R11 post-mortem: previous rotations waited (vmcnt) on loads issued only 1-3 phases
// earlier -> exposed L2/HBM latency every K-tile (the m97 stall reproduced). This
// rotation gives every half-tile >=2-5 phases of lead, m201-style:
//   Group g (4 quadrant phases, reads tile g from buf[g&1], B reg-cached in b[4][2]):
//     p0: LDA(0)+LDB(0); stage A-h0(g+1) -> buf[(g+1)&1]
//     p1: LDB(1);        stage A-h1(g+1) -> buf[(g+1)&1]
//     p2: LDA(1);        stage B-h0(g+2) -> buf[g&1]      (B regions free after p1)
//     p3: (no ds_reads); stage B-h1(g+2) -> buf[g&1]; VMCNT(4); BAR; MFMA; BAR
//   vmcnt(4) at p3: outstanding = B(g+1)[4, staged LAST group] + 8 this group; draining
//   to 4 confirms B(g+1) + A(g+1) (tile g+1 complete, published by the barrier), leaves
//   only B(g+2) in flight. Region recycling: A of bufN last read group g-1 p2; B of bufC
//   last read p1 this group — both drained >=1 barrier before their stage.
// Prologue: A(0),B(0) -> buf0, B(1) -> buf1, vmcnt(4) (leaves B(1)) — steady invariant.
// 8-slot XOR swizzle via pre-swizzled global source + XOR'd ds_read (rule #21).
template<bool OUT_BF16, int NBX>
__global__ __launch_bounds__(512, 2) void gemm256(const u16* __restrict__ A,
                                                  const u16* __restrict__ W,
                                                  void* __restrict__ Cout,
                                                  int M, int N, int K) {
    __shared__ u16 As[2][16384];
    __shared__ u16 Bs[2][16384];
    int t = threadIdx.x, lane = t & 63, w = t >> 6;          // 8 waves
    int quad = lane >> 4, l16 = lane & 15, l7 = lane & 7;
    int wm = w >> 2, wn = w & 3;                              // 2M x 4N wave grid
    int bid = blockIdx.x;
    int xcd = bid & 7, grp = bid >> 3;
    int bx = grp % NBX, by = (grp / NBX) * 8 + xcd;
    size_t m0 = (size_t)by * 256, n0 = (size_t)bx * 256;

    // staging lane map: row += lane>>3, 16B unit = (lane&7) ^ (lane>>3)  (XOR swizzle)
    int srow = lane >> 3;
    int sunit = (lane & 7) ^ srow;
    const u16* Ag = A + (m0 + srow) * (size_t)K + sunit * 8;
    const u16* Bg = W + (n0 + srow) * (size_t)K + sunit * 8;

#define STG_A(pl, tk, r0) GLDS16(Ag + ((size_t)((r0) + w * 8)) * K + (size_t)(tk) * 64, (pl) + ((r0) + w * 8) * 64)
#define STG_B(pl, tk, r0) GLDS16(Bg + ((size_t)((r0) + w * 8)) * K + (size_t)(tk) * 64, (pl) + ((r0) + w * 8) * 64)

#define LDA(pl, mh) { \
    _Pragma("unroll") for (int i_ = 0; i_ < 4; i_++) \
    _Pragma("unroll") for (int k_ = 0; k_ < 2; k_++) \
        a[i_][k_] = *(const short8*)&(pl)[(wm * 128 + (mh) * 64 + i_ * 16 + l16) * 64 + (((quad + 4 * k_) ^ l7) << 3)]; }
#define LDB(pl, nh) { \
    _Pragma("unroll") for (int j_ = 0; j_ < 2; j_++) \
    _Pragma("unroll") for (int k_ = 0; k_ < 2; k_++) \
        b[(nh) * 2 + j_][k_] = *(const short8*)&(pl)[(wn * 64 + (nh) * 32 + j_ * 16 + l16) * 64 + (((quad + 4 * k_) ^ l7) << 3)]; }
#define MFMA_Q(mh, nh) { \
    __builtin_amdgcn_s_setprio(1); \
    _Pragma("unroll") for (int i_ = 0; i_ < 4; i_++) \
    _Pragma("unroll") for (int j_ = 0; j_ < 2; j_++) \
    _Pragma("unroll") for (int k_ = 0; k_ < 2; k_++) \
        acc[(mh) * 4 + i_][(nh) * 2 + j_] = __builtin_amdgcn_mfma_f32_16x16x32_bf16( \
            a[i_][k_], b[(nh) * 2 + j_][k_], acc[(mh) * 4 + i_][(nh) * 2 + j_], 0, 0, 0); \
    __builtin_amdgcn_s_setprio(0); }

// one group = 4 quadrant phases of K-tile g; reads (pA,pB); stages A(g+1)->pAn, B(g+2)->pB
#define GROUP(g, pA, pB, pAn, sA1, sB2, lastv) { \
    LDA(pA, 0); LDB(pB, 0); \
    if (sA1) { STG_A(pAn, (g) + 1, 0); STG_A(pAn, (g) + 1, 64); } \
    BAR(); LGKM0(); MFMA_Q(0, 0); BAR(); \
    LDB(pB, 1); \
    if (sA1) { STG_A(pAn, (g) + 1, 128); STG_A(pAn, (g) + 1, 192); } \
    BAR(); LGKM0(); MFMA_Q(0, 1); BAR(); \
    LDA(pA, 1); \
    if (sB2) { STG_B(pB, (g) + 2, 0); STG_B(pB, (g) + 2, 64); } \
    BAR(); LGKM0(); MFMA_Q(1, 0); BAR(); \
    if (sB2) { STG_B(pB, (g) + 2, 128); STG_B(pB, (g) + 2, 192); } \
    if (lastv) { VMCNT0(); } else { VMCNT4(); } \
    BAR(); MFMA_Q(1, 1); BAR(); \
}

    f4 acc[8][4];
    #pragma unroll
    for (int i = 0; i < 8; i++)
        #pragma unroll
        for (int j = 0; j < 4; j++) acc[i][j] = (f4){0.f, 0.f, 0.f, 0.f};

    int NT = K >> 6;      // K-tiles of BK=64
    int NI = NT >> 1;     // groups processed in parity pairs

    u16* A0p = &As[0][0]; u16* A1p = &As[1][0];
    u16* B0p = &Bs[0][0]; u16* B1p = &Bs[1][0];

    // prologue: A(0),B(0) -> buf0; B(1) -> buf1 (issued LAST so vmcnt(4) leaves exactly it)
    #pragma unroll
    for (int r0 = 0; r0 < 256; r0 += 64) STG_A(A0p, 0, r0);
    #pragma unroll
    for (int r0 = 0; r0 < 256; r0 += 64) STG_B(B0p, 0, r0);
    #pragma unroll
    for (int r0 = 0; r0 < 256; r0 += 64) STG_B(B1p, 1, r0);
    VMCNT4();
    BAR();

    short8 a[4][2], b[4][2];
    for (int it = 0; it < NI; it++) {
        int g0 = 2 * it, g1 = 2 * it + 1;
        GROUP(g0, A0p, B0p, A1p, true, (g0 + 2 < NT), false);
        GROUP(g1, A1p, B1p, A0p, (g1 + 1 < NT), (g1 + 2 < NT), it == NI - 1);
    }

    #pragma unroll
    for (int i = 0; i < 8; i++) {
        size_t row = m0 + wm * 128 + i * 16 + quad * 4;
        #pragma unroll
        for (int j = 0; j < 4; j++) {
            size_t col = n0 + wn * 64 + j * 16 + l16;
            #pragma unroll
            for (int r = 0; r < 4; r++) {
                if (OUT_BF16) ((u16*)Cout)[(row + r) * (size_t)N + col] = f2bf(acc[i][j][r]);
                else          ((float*)Cout)[(row + r) * (size_t)N + col] = acc[i][j][r];
            }
        }
    }
#undef STG_A
#undef STG_B
#undef LDA
#undef LDB
#undef MFMA_Q
#undef GROUP
}

// ---------------- pack K (with fused RoPE) into swizzled row-major tiles (R3) ----------------
__global__ __launch_bounds__(256) void pack_k(const u16* __restrict__ QKV,
                                              const float* __restrict__ freqs,
                                              u16* __restrict__ Kp) {
    int gid = blockIdx.x * 256 + threadIdx.x;   // 262144
    int u = gid & 15, row = (gid >> 4) & 63, kt = (gid >> 10) & 31, bk = gid >> 15;
    int b = bk >> 2, kvh = bk & 3;
    int s = kt * 64 + row;
    int d8 = u ^ (row & 7);
    const u16* src = QKV + (size_t)(b * S_ + s) * 3072 + 2048 + kvh * HD_ + d8 * 8;
    short8 v = *(const short8*)src;
    short8 o;
    #pragma unroll
    for (int jp = 0; jp < 4; jp++) {
        float2 cw = ((const float2*)freqs)[s * 64 + d8 * 4 + jp];
        float x0 = bf2f((u16)v[2 * jp]), x1 = bf2f((u16)v[2 * jp + 1]);
        o[2 * jp]     = (short)f2bf(x0 * cw.x - x1 * cw.y);
        o[2 * jp + 1] = (short)f2bf(x0 * cw.y + x1 * cw.x);
    }
    *(short8*)&Kp[(size_t)gid * 8] = o;
}

// ---------------- pack V transposed (Vt[hd][k]) with same XOR swizzle (R3) ----------------
__global__ __launch_bounds__(256) void pack_v(const u16* __restrict__ QKV, u16* __restrict__ Vp) {
    __shared__ u16 L[64 * 136];
    int bid = blockIdx.x;          // 256 blocks
    int bk = bid & 7, kt = bid >> 3;
    int b = bk >> 2, kvh = bk & 3;
    int t = threadIdx.x;
    const u16* src = QKV + (size_t)(b * S_ + kt * 64) * 3072 + 2560 + kvh * HD_;
    #pragma unroll
    for (int it = 0; it < 4; it++) {
        int idx = t + it * 256;
        int r = idx >> 4, c = idx & 15;
        *(short8*)&L[r * 136 + c * 8] = *(const short8*)(src + (size_t)r * 3072 + c * 8);
    }
    __syncthreads();
    u16* dst = Vp + (size_t)(bk * 32 + kt) * 8192;
    #pragma unroll
    for (int it = 0; it < 4; it++) {
        int idx = t + it * 256;     // 1024 units: hd = idx>>3, u = idx&7
        int hd = idx >> 3, u = idx & 7;
        int k0 = (u ^ (hd & 7)) * 8;
        short8 v;
        #pragma unroll
        for (int jj = 0; jj < 8; jj++) v[jj] = (short)L[(k0 + jj) * 136 + hd];
        *(short8*)&dst[(size_t)idx * 8] = v;
    }
}

// ---------------- Flash attention: R3 version verbatim (structural floor ~78 us) ----------
__global__ __launch_bounds__(256) __attribute__((amdgpu_waves_per_eu(2, 2)))
void attn_kernel(const u16* __restrict__ QKV,
                 const float* __restrict__ freqs,
                 const u16* __restrict__ Kp,
                 const u16* __restrict__ Vp,
                 u16* __restrict__ Ob) {
    __shared__ u16 Ks[2][8192];    // 2 x 16KB K tile [64 rows][128 d], XOR-swizzled
    __shared__ u16 Vs[2][8192];    // 2 x 16KB V^T tile [128 hd][64 k], XOR-swizzled
    int bid = blockIdx.x;          // 512
    int jj_ = bid & 255, half = bid >> 8;
    int bk = jj_ & 7, qpr = jj_ >> 3;        // qpr in [0,32)
    int qb = half ? qpr : 63 - qpr;          // long tiles dispatched first
    int b = bk >> 2, kvh = bk & 3;
    int t = threadIdx.x, lane = t & 63, w = t >> 6;
    int l31 = lane & 31, hi = lane >> 5, l7 = lane & 7;
    int h = kvh * 4 + w;
    int nkt = (qb >> 1) + 1;

    // ---- Q: 32 rows (row = l31), RoPE + KSCALE in-register, B-fragment layout ----
    short8 qf[8];
    {
        int s = qb * 32 + l31;
        const u16* qp = QKV + ((size_t)(b * S_ + s)) * 3072 + h * HD_ + hi * 8;
        const float2* fr2 = (const float2*)freqs;
        #pragma unroll
        for (int ds = 0; ds < 8; ds++) {
            short8 v = *(const short8*)(qp + ds * 16);
            short8 o;
            #pragma unroll
            for (int jp = 0; jp < 4; jp++) {
                float2 cs = fr2[s * 64 + ds * 8 + hi * 4 + jp];
                float x0 = bf2f((u16)v[2 * jp]), x1 = bf2f((u16)v[2 * jp + 1]);
                o[2 * jp]     = (short)f2bf((x0 * cs.x - x1 * cs.y) * KSCALE);
                o[2 * jp + 1] = (short)f2bf((x0 * cs.y + x1 * cs.x) * KSCALE);
            }
            qf[ds] = o;
        }
    }

    float m_i = -3e38f, ls = 0.f;
    f16v o4[4];
    #pragma unroll
    for (int i = 0; i < 4; i++)
        #pragma unroll
        for (int r = 0; r < 16; r++) o4[i][r] = 0.f;

    const u16* Kpb = Kp + (size_t)bk * 32 * 8192;
    const u16* Vpb = Vp + (size_t)bk * 32 * 8192;
    int so = w * 2048 + lane * 8;   // this lane's staging slot (u16 units)

    // initial stage of tile 0 into buffer 0 (wave w stages its 4KB quarter of K and V)
    {
        const u16* ks = Kpb + so;
        const u16* vs = Vpb + so;
        #pragma unroll
        for (int i = 0; i < 4; i++) {
            GLDS16(ks + i * 512, &Ks[0][w * 2048 + i * 512]);
            GLDS16(vs + i * 512, &Vs[0][w * 2048 + i * 512]);
        }
    }

    for (int kt = 0; kt < nkt; kt++) {
        int buf = kt & 1;
        __syncthreads();   // drains the stage of tile kt (issued one iteration ago)
        if (kt + 1 < nkt) {
            int nb = buf ^ 1;
            const u16* ks = Kpb + (size_t)(kt + 1) * 8192 + so;
            const u16* vs = Vpb + (size_t)(kt + 1) * 8192 + so;
            #pragma unroll
            for (int i = 0; i < 4; i++) {
                GLDS16(ks + i * 512, &Ks[nb][w * 2048 + i * 512]);
                GLDS16(vs + i * 512, &Vs[nb][w * 2048 + i * 512]);
            }
        }

        // ---- S^T = K . Q^T : D rows = k-pos (crow layout), cols = q (lane&31) ----
        f16v sacc[2];
        #pragma unroll
        for (int k2 = 0; k2 < 2; k2++)
            #pragma unroll
            for (int r = 0; r < 16; r++) sacc[k2][r] = 0.f;
        #pragma unroll
        for (int ds = 0; ds < 8; ds++) {
            int uK = ((ds * 2 + hi) ^ l7) * 8;
            short8 kf0 = *(const short8*)&Ks[buf][l31 * 128 + uK];
            short8 kf1 = *(const short8*)&Ks[buf][(32 + l31) * 128 + uK];
            sacc[0] = __builtin_amdgcn_mfma_f32_32x32x16_bf16(kf0, qf[ds], sacc[0], 0, 0, 0);
            sacc[1] = __builtin_amdgcn_mfma_f32_32x32x16_bf16(kf1, qf[ds], sacc[1], 0, 0, 0);
        }

        // ---- causal mask, diagonal tile only ----
        if (kt == nkt - 1) {
            int off0 = kt * 64 - qb * 32;
            #pragma unroll
            for (int k2 = 0; k2 < 2; k2++) {
                #pragma unroll
                for (int r = 0; r < 16; r++) {
                    int colo = off0 + k2 * 32 + (r & 3) + ((r >> 2) << 3) + (hi << 2);
                    if (colo > l31) sacc[k2][r] = -3e38f;
                }
            }
        }

        // ---- online softmax, per-lane scalars; defer-max THR=8 (T13) ----
        float pm = sacc[0][0];
        #pragma unroll
        for (int r = 1; r < 16; r++) pm = fmaxf(pm, sacc[0][r]);
        #pragma unroll
        for (int r = 0; r < 16; r++) pm = fmaxf(pm, sacc[1][r]);
        pm = fmaxf(pm, __shfl_xor(pm, 32, 64));
        if (__any(pm > m_i + 8.0f)) {
            float mnew = fmaxf(m_i, pm);
            float al = exp2f(m_i - mnew);
            ls *= al;
            #pragma unroll
            for (int i = 0; i < 4; i++)
                #pragma unroll
                for (int r = 0; r < 16; r++) o4[i][r] *= al;
            m_i = mnew;
        }

        // ---- P = exp2(S - m); assemble PV B-fragments in-register (T12) ----
        short8 pa[4];
        #pragma unroll
        for (int k2 = 0; k2 < 2; k2++) {
            float p[16];
            #pragma unroll
            for (int r = 0; r < 16; r++) {
                p[r] = exp2f(sacc[k2][r] - m_i);
                ls += p[r];
            }
            unsigned W0 = pk_bf16(p[0], p[1]),   W1 = pk_bf16(p[2], p[3]);
            unsigned W2 = pk_bf16(p[4], p[5]),   W3 = pk_bf16(p[6], p[7]);
            unsigned W4 = pk_bf16(p[8], p[9]),   W5 = pk_bf16(p[10], p[11]);
            unsigned W6 = pk_bf16(p[12], p[13]), W7 = pk_bf16(p[14], p[15]);
            uint2v r02 = __builtin_amdgcn_permlane32_swap(W0, W2, false, false);
            uint2v r13 = __builtin_amdgcn_permlane32_swap(W1, W3, false, false);
            uint2v r46 = __builtin_amdgcn_permlane32_swap(W4, W6, false, false);
            uint2v r57 = __builtin_amdgcn_permlane32_swap(W5, W7, false, false);
            union { unsigned u[4]; short8 s8; } flo, fhi;
            flo.u[0] = r02[0]; flo.u[1] = r13[0]; flo.u[2] = r02[1]; flo.u[3] = r13[1];
            fhi.u[0] = r46[0]; fhi.u[1] = r57[0]; fhi.u[2] = r46[1]; fhi.u[3] = r57[1];
            pa[k2 * 2]     = flo.s8;
            pa[k2 * 2 + 1] = fhi.s8;
        }

        // ---- O^T += V^T . P^T ----
        #pragma unroll
        for (int ks = 0; ks < 4; ks++) {
            int uV = ((ks * 2 + hi) ^ l7) * 8;
            #pragma unroll
            for (int ht = 0; ht < 4; ht++) {
                short8 vf = *(const short8*)&Vs[buf][(ht * 32 + l31) * 64 + uV];
                o4[ht] = __builtin_amdgcn_mfma_f32_32x32x16_bf16(vf, pa[ks], o4[ht], 0, 0, 0);
            }
        }
    }

    // ---- epilogue ----
    ls += __shfl_xor(ls, 32, 64);
    float rl = 1.0f / ls;
    size_t row = (size_t)b * S_ + qb * 32 + l31;
    u16* op = Ob + row * 2048 + h * HD_;
    #pragma unroll
    for (int ht = 0; ht < 4; ht++) {
        #pragma unroll
        for (int g = 0; g < 4; g++) {
            ushort4 st;
            st.x = f2bf(o4[ht][4 * g + 0] * rl);
            st.y = f2bf(o4[ht][4 * g + 1] * rl);
            st.z = f2bf(o4[ht][4 * g + 2] * rl);
            st.w = f2bf(o4[ht][4 * g + 3] * rl);
            *(ushort4*)&op[ht * 32 + g * 8 + hi * 4] = st;
        }
    }
}

extern "C" void kernel_launch(void* const* d_in, const int* in_sizes, int n_in,
                              void* d_out, int out_size, void* d_ws, size_t ws_size,
                              hipStream_t stream) {
    const float* x     = (const float*)d_in[0];
    const float* freqs = (const float*)d_in[1];
    const float* wq    = (const float*)d_in[2];
    const float* wk    = (const float*)d_in[3];
    const float* wv    = (const float*)d_in[4];
    const float* wo    = (const float*)d_in[5];
    float* out = (float*)d_out;

    char* p = (char*)d_ws;
    u16* xb    = (u16*)p; p += (size_t)4096 * 2048 * 2;   // 16MB
    u16* wqkvb = (u16*)p; p += (size_t)3072 * 2048 * 2;   // 12MB
    u16* wob   = (u16*)p; p += (size_t)2048 * 2048 * 2;   // 8MB
    u16* QKVb  = (u16*)p; p += (size_t)4096 * 3072 * 2;   // 24MB
    u16* Kpb   = (u16*)p; p += (size_t)8 * 32 * 8192 * 2; // 4MB
    u16* Vpb   = (u16*)p; p += (size_t)8 * 32 * 8192 * 2; // 4MB
    u16* attnb = xb;  // reuse: x not needed after QKV GEMM

    cast_all<<<18432, 256, 0, stream>>>(x, wq, wk, wv, wo, xb, wqkvb, wob);

    gemm256<true, 12><<<192, 512, 0, stream>>>(xb, wqkvb, QKVb, 4096, 3072, 2048);

    pack_k<<<1024, 256, 0, stream>>>(QKVb, freqs, Kpb);
    pack_v<<<256, 256, 0, stream>>>(QKVb, Vpb);

    attn_kernel<<<512, 256, 0, stream>>>(QKVb, freqs, Kpb, Vpb, attnb);

    gemm256<false, 8><<<128, 512, 0, stream>>>(attnb, wob, out, 4096, 2048, 2048);
}